// Round 1
// baseline (1402.893 us; speedup 1.0000x reference)
//
#include <hip/hip_runtime.h>
#include <hip/hip_fp16.h>
#include <cstdint>

#define B_   4
#define S_   19
#define HW_  16384
#define P_   65536
#define C_   256
#define Q_   256
#define NEG_ 512
#define NS_  131072
#define GENV_ 144

// ---------------- threefry2x32 (JAX-exact) ----------------
__device__ __forceinline__ void tf2x32(uint32_t k0, uint32_t k1, uint32_t x0, uint32_t x1,
                                       uint32_t& o0, uint32_t& o1) {
  uint32_t k2 = k0 ^ k1 ^ 0x1BD11BDAu;
#define TFR(r) { x0 += x1; x1 = (x1 << r) | (x1 >> (32 - r)); x1 ^= x0; }
  x0 += k0; x1 += k1;
  TFR(13) TFR(15) TFR(26) TFR(6)  x0 += k1; x1 += k2 + 1u;
  TFR(17) TFR(29) TFR(16) TFR(24) x0 += k2; x1 += k0 + 2u;
  TFR(13) TFR(15) TFR(26) TFR(6)  x0 += k0; x1 += k1 + 3u;
  TFR(17) TFR(29) TFR(16) TFR(24) x0 += k1; x1 += k2 + 4u;
  TFR(13) TFR(15) TFR(26) TFR(6)  x0 += k2; x1 += k0 + 5u;
#undef TFR
  o0 = x0; o1 = x1;
}

// partitionable-mode random_bits: bits[n] = y0 ^ y1 of tf(key, (0, n))
__device__ __forceinline__ uint32_t rbits(uint32_t k0, uint32_t k1, uint32_t n) {
  uint32_t a, b; tf2x32(k0, k1, 0u, n, a, b); return a ^ b;
}

__device__ __forceinline__ float bits2f01(uint32_t b) {
  return __uint_as_float((b >> 9) | 0x3f800000u) - 1.0f;
}

__device__ __forceinline__ float fastrcp(float x) {
  float r; asm("v_rcp_f32 %0, %1" : "=v"(r) : "v"(x)); return r;
}
__device__ __forceinline__ float fastrsq(float x) {
  float r; asm("v_rsq_f32 %0, %1" : "=v"(r) : "v"(x)); return r;
}

__device__ __forceinline__ float wred(float v) {
#pragma unroll
  for (int off = 32; off > 0; off >>= 1) v += __shfl_xor(v, off, 64);
  return v;
}
__device__ __forceinline__ void wred5(float& a, float& b, float& c, float& d, float& e) {
#pragma unroll
  for (int off = 32; off > 0; off >>= 1) {
    a += __shfl_xor(a, off, 64);
    b += __shfl_xor(b, off, 64);
    c += __shfl_xor(c, off, 64);
    d += __shfl_xor(d, off, 64);
    e += __shfl_xor(e, off, 64);
  }
}
__device__ __forceinline__ void wred2(float& a, float& b) {
#pragma unroll
  for (int off = 32; off > 0; off >>= 1) {
    a += __shfl_xor(a, off, 64);
    b += __shfl_xor(b, off, 64);
  }
}

// XLA ErfInv32 (Giles) — matches lax.erf_inv closely
__device__ __forceinline__ float erfinv_f(float x) {
  float w = -__logf(fmaxf(fmaf(-x, x, 1.0f), 1e-37f));
  float p;
  if (w < 5.0f) {
    w -= 2.5f;
    p = 2.81022636e-08f;
    p = fmaf(p, w, 3.43273939e-07f);
    p = fmaf(p, w, -3.5233877e-06f);
    p = fmaf(p, w, -4.39150654e-06f);
    p = fmaf(p, w, 0.00021858087f);
    p = fmaf(p, w, -0.00125372503f);
    p = fmaf(p, w, -0.00417768164f);
    p = fmaf(p, w, 0.246640727f);
    p = fmaf(p, w, 1.50140941f);
  } else {
    w = sqrtf(w) - 3.0f;
    p = -0.000200214257f;
    p = fmaf(p, w, 0.000100950558f);
    p = fmaf(p, w, 0.00134934322f);
    p = fmaf(p, w, -0.00367342844f);
    p = fmaf(p, w, 0.00573950773f);
    p = fmaf(p, w, -0.0076224613f);
    p = fmaf(p, w, 0.00943887047f);
    p = fmaf(p, w, 1.00167406f);
    p = fmaf(p, w, 2.83297682f);
  }
  return p * x;
}

union F4 { float4 f; __half2 h[4]; float a[4]; };

// ---------------- K0: per-class keys: fold_in(key(1234), i) then foldlike split(4) ----------------
__global__ void k_keys(uint32_t* __restrict__ keys) {
  int i = threadIdx.x;
  if (i >= S_) return;
  uint32_t f0, f1;
  tf2x32(0u, 1234u, 0u, (uint32_t)i, f0, f1);
#pragma unroll
  for (int t = 0; t < 4; ++t) {
    uint32_t a, b;
    tf2x32(f0, f1, 0u, (uint32_t)t, a, b);
    keys[i * 8 + t * 2] = a; keys[i * 8 + t * 2 + 1] = b;  // anc,cls,neg,gen
  }
}

// ---------------- K1: class id + hard flag per pixel ----------------
__global__ __launch_bounds__(256) void k_classify(const float* __restrict__ label,
    const float* __restrict__ mask, const float* __restrict__ prob,
    int* __restrict__ cls, int* __restrict__ hrd) {
  int p = blockIdx.x * 256 + threadIdx.x;
  int b = p >> 14, rem = p & (HW_ - 1);
  int sp = -1;
#pragma unroll
  for (int s = 0; s < S_; ++s) {
    float l = label[((b * S_ + s) << 14) + rem];
    if (l > 0.5f) sp = s;
  }
  if (mask[(b << 14) + rem] <= 0.5f) sp = -1;
  int h = 0;
  if (sp >= 0) h = (prob[((b * S_ + sp) << 14) + rem] < 0.97f) ? 1 : 0;
  cls[p] = sp; hrd[p] = h;
}

// ---------------- K1b: pack (B,C,H,W) f32 mu/sigma -> (P,C) half2 interleaved ----------------
__global__ __launch_bounds__(256) void k_pack(const float* __restrict__ mu,
    const float* __restrict__ sg, __half2* __restrict__ pair) {
  __shared__ float smu[64][65];
  __shared__ float ssg[64][65];
  int p0 = blockIdx.x * 64;
  int c0 = blockIdx.y * 64;
  int b = p0 >> 14; int rem0 = p0 & (HW_ - 1);
  int px = threadIdx.x & 63, cy = threadIdx.x >> 6;
#pragma unroll
  for (int it = 0; it < 16; ++it) {
    int cl = cy + it * 4;
    int addr = ((b * C_ + c0 + cl) << 14) + rem0 + px;
    smu[cl][px] = mu[addr];
    ssg[cl][px] = sg[addr];
  }
  __syncthreads();
  int cx = threadIdx.x & 63, py = threadIdx.x >> 6;
#pragma unroll
  for (int it = 0; it < 16; ++it) {
    int pl = py + it * 4;
    int p = p0 + pl;
    pair[(size_t)p * C_ + c0 + cx] = __floats2half2_rn(smu[cx][pl], ssg[cx][pl]);
  }
}

// ---------------- K2a/b/c: ordered per-class pixel lists ----------------
__global__ __launch_bounds__(256) void k_count(const int* __restrict__ cls, const int* __restrict__ hrd,
    int* __restrict__ bcv, int* __restrict__ bch) {
  __shared__ int hv[S_], hh[S_];
  int t = threadIdx.x;
  if (t < S_) { hv[t] = 0; hh[t] = 0; }
  __syncthreads();
  int p = blockIdx.x * 256 + t;
  int s = cls[p];
  if (s >= 0) { atomicAdd(&hv[s], 1); if (hrd[p]) atomicAdd(&hh[s], 1); }
  __syncthreads();
  if (t < S_) { bcv[t * 256 + blockIdx.x] = hv[t]; bch[t * 256 + blockIdx.x] = hh[t]; }
}

__global__ __launch_bounds__(64) void k_scan(int* __restrict__ bcv, int* __restrict__ bch,
    int* __restrict__ bov, int* __restrict__ boh,
    int* __restrict__ cntv, int* __restrict__ cnth,
    int* __restrict__ basev, int* __restrict__ baseh) {
  int s = threadIdx.x;
  if (s < S_) {
    int run = 0;
    for (int b = 0; b < 256; ++b) { int v = bcv[s * 256 + b]; bov[s * 256 + b] = run; run += v; }
    cntv[s] = run;
    run = 0;
    for (int b = 0; b < 256; ++b) { int v = bch[s * 256 + b]; boh[s * 256 + b] = run; run += v; }
    cnth[s] = run;
  }
  __syncthreads();
  if (s == 0) {
    int bv = 0, bh = 0;
    for (int k = 0; k < S_; ++k) { basev[k] = bv; bv += cntv[k]; baseh[k] = bh; bh += cnth[k]; }
  }
}

__global__ __launch_bounds__(256) void k_fill(const int* __restrict__ cls, const int* __restrict__ hrd,
    const int* __restrict__ bov, const int* __restrict__ boh,
    const int* __restrict__ basev, const int* __restrict__ baseh,
    int* __restrict__ posv, int* __restrict__ posh) {
  __shared__ int lc[256], lh[256];
  int t = threadIdx.x;
  int p = blockIdx.x * 256 + t;
  int s = cls[p]; int h = hrd[p];
  lc[t] = s; lh[t] = h;
  __syncthreads();
  if (s >= 0) {
    int rv = 0, rh = 0;
    for (int k = 0; k < t; ++k) { if (lc[k] == s) { rv++; rh += lh[k]; } }
    posv[basev[s] + bov[s * 256 + blockIdx.x] + rv] = p;
    if (h) posh[baseh[s] + boh[s * 256 + blockIdx.x] + rh] = p;
  }
}

// ---------------- K3: per-class sums of 1/sg and mu/sg over all channels ----------------
__global__ __launch_bounds__(256) void k_sums(const float* __restrict__ mu, const float* __restrict__ sg,
    const int* __restrict__ cls, float* __restrict__ gA, float* __restrict__ gB) {
  __shared__ float accA[S_][C_];
  __shared__ float accB[S_][C_];
  int t = threadIdx.x;
  for (int e = t; e < S_ * C_; e += 256) { (&accA[0][0])[e] = 0.f; (&accB[0][0])[e] = 0.f; }
  __syncthreads();
  int p = blockIdx.x * 256 + t;
  int b = p >> 14, rem = p & (HW_ - 1);
  int s = cls[p];
  if (s >= 0) {
    size_t base = ((size_t)(b * C_) << 14) + rem;
    for (int c = 0; c < C_; ++c) {
      float sv = sg[base + ((size_t)c << 14)];
      float mv = mu[base + ((size_t)c << 14)];
      float ia = 1.0f / sv;
      atomicAdd(&accA[s][c], ia);
      atomicAdd(&accB[s][c], ia * mv);
    }
  }
  __syncthreads();
  for (int e = t; e < S_ * C_; e += 256) {
    atomicAdd(&gA[e], (&accA[0][0])[e]);
    atomicAdd(&gB[e], (&accB[0][0])[e]);
  }
}

// ---------------- K4: prototypes (mirror reference op-for-op) ----------------
__global__ __launch_bounds__(256) void k_proto(const float* __restrict__ gA, const float* __restrict__ gB,
    const float* __restrict__ mmu, const float* __restrict__ msg,
    float* __restrict__ pmu, float* __restrict__ psig, float* __restrict__ phat) {
  int s = blockIdx.x, c = threadIdx.x;
  int e = s * C_ + c;
  float A = gA[e], Bv = gB[e];
  float psb = 1.0f / A;
  float pmb = psb * Bv;
  float ms = msg[e], mm = mmu[e];
  float ps = 1.0f / (1.0f / psb + 1.0f / ms);
  float pm = ps * (mm / ms + pmb / psb);
  pmu[e] = pm; psig[e] = ps;
  __shared__ float red[4];
  float w = wred(pm * pm);
  int lane = c & 63, wv = c >> 6;
  if (lane == 0) red[wv] = w;
  __syncthreads();
  float tot = red[0] + red[1] + red[2] + red[3];
  float nrm = fmaxf(sqrtf(tot), 1e-12f);
  phat[e] = pm / nrm;
}

// ---------------- K5a: sim over others -> log_softmax(sim/TEMP) ----------------
__global__ __launch_bounds__(64) void k_simlogp(const float* __restrict__ phat,
    const float* __restrict__ psig, float* __restrict__ logp) {
  int i = blockIdx.x, lane = threadIdx.x;
  int c0 = lane * 4;
  float phi[4], psi[4];
#pragma unroll
  for (int k = 0; k < 4; ++k) { phi[k] = phat[i * C_ + c0 + k]; psi[k] = psig[i * C_ + c0 + k]; }
  float xs[18];
#pragma unroll
  for (int j = 0; j < 18; ++j) {
    int o = i + 1 + j; if (o >= S_) o -= S_;
    float t = 0.f;
#pragma unroll
    for (int k = 0; k < 4; ++k) {
      float d = phi[k] - phat[o * C_ + c0 + k];
      float dn = psi[k] + psig[o * C_ + c0 + k];
      t += d * d / dn + logf(dn);
    }
    t = wred(t);
    xs[j] = (-0.5f * t * (1.0f / 256.0f)) * 2.0f;  // sim / TEMP
  }
  float m = xs[0];
#pragma unroll
  for (int j = 1; j < 18; ++j) m = fmaxf(m, xs[j]);
  float se = 0.f;
#pragma unroll
  for (int j = 0; j < 18; ++j) se += expf(xs[j] - m);
  float lg = logf(se);
  if (lane == 0) {
#pragma unroll
    for (int j = 0; j < 18; ++j) logp[i * 18 + j] = xs[j] - m - lg;
  }
}

// ---------------- K5d: anchor indices ----------------
__global__ __launch_bounds__(256) void k_anchors(const uint32_t* __restrict__ keys,
    const int* __restrict__ cnth, const int* __restrict__ baseh,
    const int* __restrict__ posh, int* __restrict__ aidx) {
  int i = blockIdx.x, q = threadIdx.x;
  uint32_t k0 = keys[i * 8 + 0], k1 = keys[i * 8 + 1];
  float u = bits2f01(rbits(k0, k1, (uint32_t)q));
  int cnt = cnth[i];
  int idx = P_ - 1;
  if (cnt > 0) {
    int kk = (int)(u * (float)cnt);
    if (kk >= cnt) kk = cnt - 1;
    idx = posh[baseh[i] + kk];
  }
  aidx[i * Q_ + q] = idx;
}

// ---------------- K5c: generalized prototypes (normal -> normalize) ----------------
__global__ __launch_bounds__(256) void k_gen(const uint32_t* __restrict__ keys,
    const float* __restrict__ pmu, const float* __restrict__ psig, float* __restrict__ ghat) {
  int v = blockIdx.x, i = blockIdx.y, c = threadIdx.x;
  int o = i + 1 + (v >> 3); if (o >= S_) o -= S_;
  uint32_t k0 = keys[i * 8 + 6], k1 = keys[i * 8 + 7];
  uint32_t bits = rbits(k0, k1, (uint32_t)(v * C_ + c));
  float f01 = bits2f01(bits);
  const float lo = -0.99999994f;
  float u = fmaxf(f01 * 2.0f + lo, lo);
  float eps = 1.41421356237f * erfinv_f(u);
  float g = pmu[o * C_ + c] + sqrtf(psig[o * C_ + c]) * eps;
  __shared__ float red[4];
  float w = wred(g * g);
  int lane = c & 63, wv = c >> 6;
  if (lane == 0) red[wv] = w;
  __syncthreads();
  float tot = red[0] + red[1] + red[2] + red[3];
  float nrm = fmaxf(sqrtf(tot), 1e-12f);
  ghat[((size_t)(i * GENV_ + v)) * C_ + c] = g / nrm;
}

// ---------------- K5b: categorical class sampling + negative pixel sampling ----------------
__global__ __launch_bounds__(256) void k_sample(const uint32_t* __restrict__ keys,
    const float* __restrict__ logp, const int* __restrict__ cntv, const int* __restrict__ basev,
    const int* __restrict__ posv, int* __restrict__ nidx) {
  int i = blockIdx.y;
  int m = blockIdx.x * 256 + threadIdx.x;  // 0..131071
  __shared__ float lp[18];
  __shared__ int lcnt[S_], lbase[S_];
  int t = threadIdx.x;
  if (t < 18) lp[t] = logp[i * 18 + t];
  if (t < S_) { lcnt[t] = cntv[t]; lbase[t] = basev[t]; }
  __syncthreads();
  uint32_t kc0 = keys[i * 8 + 2], kc1 = keys[i * 8 + 3];
  uint32_t kn0 = keys[i * 8 + 4], kn1 = keys[i * 8 + 5];
  float bv = -1e30f; int best = 0;
  for (int s = 0; s < 18; ++s) {
    uint32_t b = rbits(kc0, kc1, (uint32_t)m * 18u + (uint32_t)s);
    float u = fmaxf(bits2f01(b), 1.17549435e-38f);
    float g = -__logf(-__logf(u)) + lp[s];
    if (g > bv) { bv = g; best = s; }
  }
  float un = bits2f01(rbits(kn0, kn1, (uint32_t)m));
  int cc = i + 1 + best; if (cc >= S_) cc -= S_;
  int cnt = lcnt[cc];
  int idx = P_ - 1;
  if (cnt > 0) {
    int kk = (int)(un * (float)cnt);
    if (kk >= cnt) kk = cnt - 1;
    idx = posv[lbase[cc] + kk];
  }
  nidx[(size_t)i * NS_ + m] = idx;
}

// ---------------- K6: main — one wave per (class, anchor), 657 candidates, online LSE ----------------
__global__ __launch_bounds__(256) void k_main(const __half2* __restrict__ pair,
    const float* __restrict__ phat, const float* __restrict__ psig,
    const float* __restrict__ ghat, const int* __restrict__ aidx,
    const int* __restrict__ nidx, float* __restrict__ out) {
  int wv = threadIdx.x >> 6, lane = threadIdx.x & 63;
  int A = blockIdx.x * 4 + wv;
  int i = A >> 8, q = A & 255;
  int c0 = lane << 2;

  int ap = aidx[A];
  F4 ua; ua.f = *reinterpret_cast<const float4*>(pair + (size_t)ap * C_ + c0);
  float amu[4], asg[4];
#pragma unroll
  for (int k = 0; k < 4; ++k) { amu[k] = __low2float(ua.h[k]); asg[k] = __high2float(ua.h[k]); }
  float s2 = 0.f;
#pragma unroll
  for (int k = 0; k < 4; ++k) s2 = fmaf(amu[k], amu[k], s2);
  s2 = wred(s2);
  float rn = 1.0f / fmaxf(sqrtf(s2), 1e-12f);
  float ahat[4], ah2[4], w[4], ahw[4];
  float A1l = 0.f, Lal = 0.f;
#pragma unroll
  for (int k = 0; k < 4; ++k) {
    ahat[k] = amu[k] * rn;
    ah2[k] = ahat[k] * ahat[k];
    w[k] = fastrcp(asg[k]);
    ahw[k] = ahat[k] * w[k];
    A1l = fmaf(ah2[k], w[k], A1l);
    Lal += __logf(asg[k]);
  }
  wred2(A1l, Lal);
  float A1 = A1l, La = Lal;

  // pos candidate (index 0)
  float tp = 0.f;
  {
    F4 p4, s4;
    p4.f = *reinterpret_cast<const float4*>(phat + i * C_ + c0);
    s4.f = *reinterpret_cast<const float4*>(psig + i * C_ + c0);
#pragma unroll
    for (int k = 0; k < 4; ++k) {
      float d = ahat[k] - p4.a[k];
      float dn = asg[k] + s4.a[k];
      tp = fmaf(d * d, fastrcp(dn), tp + __logf(dn));
    }
  }
  tp = wred(tp);
  float logit0 = -tp * (1.0f / 256.0f);
  float mrun = logit0, lrun = 1.0f;

  // negatives
  const int* nrow = nidx + (size_t)i * NS_ + q * NEG_;
  int idx = nrow[0];
  F4 cur; cur.f = *reinterpret_cast<const float4*>(pair + (size_t)idx * C_ + c0);
  for (int j = 0; j < NEG_; ++j) {
    F4 nxt;
    if (j + 1 < NEG_) {
      int idn = nrow[j + 1];
      nxt.f = *reinterpret_cast<const float4*>(pair + (size_t)idn * C_ + c0);
    }
    float sA = 0.f, sN = 0.f, sNR = 0.f, sC = 0.f, sL = 0.f;
#pragma unroll
    for (int k = 0; k < 4; ++k) {
      float nm = __low2float(cur.h[k]);
      float ns = __high2float(cur.h[k]);
      float dn = asg[k] + ns;
      float r = fastrcp(dn);
      sA = fmaf(ah2[k], r, sA);
      float nr = nm * r;
      sC = fmaf(ahat[k], nr, sC);
      sNR = fmaf(nm, nr, sNR);
      sN = fmaf(nm, nm, sN);
      sL += __logf(dn);
    }
    wred5(sA, sN, sNR, sC, sL);
    float rn1 = fastrsq(sN);
    float rn2 = fastrcp(sN);
    float tt = sA + rn2 * sNR - 2.0f * rn1 * sC + sL;
    float lg = -tt * (1.0f / 256.0f);
    if (lg > mrun) { lrun = lrun * __expf(mrun - lg) + 1.0f; mrun = lg; }
    else lrun += __expf(lg - mrun);
    if (j + 1 < NEG_) cur = nxt;
  }

  // generalized candidates (sg = 0): factorized
  const float* gb = ghat + (size_t)i * GENV_ * C_;
  for (int v = 0; v < GENV_; ++v) {
    F4 g4; g4.f = *reinterpret_cast<const float4*>(gb + v * C_ + c0);
    float a1 = 0.f, a2 = 0.f;
#pragma unroll
    for (int k = 0; k < 4; ++k) {
      a1 = fmaf(g4.a[k] * g4.a[k], w[k], a1);
      a2 = fmaf(g4.a[k], ahw[k], a2);
    }
    wred2(a1, a2);
    float lg = -(A1 - 2.0f * a2 + a1 + La) * (1.0f / 256.0f);
    if (lg > mrun) { lrun = lrun * __expf(mrun - lg) + 1.0f; mrun = lg; }
    else lrun += __expf(lg - mrun);
  }

  float lse = mrun + __logf(lrun);
  float contrib = logit0 - lse;
  if (lane == 0) atomicAdd(out, -contrib * (1.0f / (19.0f * 256.0f)));
}

// ---------------- host ----------------
extern "C" void kernel_launch(void* const* d_in, const int* in_sizes, int n_in,
                              void* d_out, int out_size, void* d_ws, size_t ws_size,
                              hipStream_t stream) {
  const float* mu    = (const float*)d_in[0];
  const float* sg    = (const float*)d_in[1];
  const float* label = (const float*)d_in[2];
  const float* mask  = (const float*)d_in[3];
  const float* prob  = (const float*)d_in[4];
  const float* mmu   = (const float*)d_in[5];
  const float* msg   = (const float*)d_in[6];

  char* ws = (char*)d_ws;
  size_t off = 0;
  auto take = [&](size_t bytes) { size_t r = off; off = (off + bytes + 255) & ~(size_t)255; return r; };
  size_t o_pair  = take((size_t)P_ * C_ * 4);
  size_t o_cls   = take((size_t)P_ * 4);
  size_t o_hrd   = take((size_t)P_ * 4);
  size_t o_bcv   = take(S_ * 256 * 4);
  size_t o_bch   = take(S_ * 256 * 4);
  size_t o_bov   = take(S_ * 256 * 4);
  size_t o_boh   = take(S_ * 256 * 4);
  size_t o_cntv  = take(S_ * 4);
  size_t o_cnth  = take(S_ * 4);
  size_t o_basev = take(S_ * 4);
  size_t o_baseh = take(S_ * 4);
  size_t o_posv  = take((size_t)P_ * 4);
  size_t o_posh  = take((size_t)P_ * 4);
  size_t o_gAB   = take((size_t)2 * S_ * C_ * 4);
  size_t o_pmu   = take(S_ * C_ * 4);
  size_t o_psig  = take(S_ * C_ * 4);
  size_t o_phat  = take(S_ * C_ * 4);
  size_t o_logp  = take(S_ * 18 * 4);
  size_t o_keys  = take(S_ * 8 * 4);
  size_t o_aidx  = take(S_ * Q_ * 4);
  size_t o_nidx  = take((size_t)S_ * NS_ * 4);
  size_t o_ghat  = take((size_t)S_ * GENV_ * C_ * 4);
  if (ws_size < off) return;

  __half2*  pairp = (__half2*)(ws + o_pair);
  int*      cls   = (int*)(ws + o_cls);
  int*      hrd   = (int*)(ws + o_hrd);
  int*      bcv   = (int*)(ws + o_bcv);
  int*      bch   = (int*)(ws + o_bch);
  int*      bov   = (int*)(ws + o_bov);
  int*      boh   = (int*)(ws + o_boh);
  int*      cntv  = (int*)(ws + o_cntv);
  int*      cnth  = (int*)(ws + o_cnth);
  int*      basev = (int*)(ws + o_basev);
  int*      baseh = (int*)(ws + o_baseh);
  int*      posv  = (int*)(ws + o_posv);
  int*      posh  = (int*)(ws + o_posh);
  float*    gA    = (float*)(ws + o_gAB);
  float*    gB    = gA + S_ * C_;
  float*    pmu   = (float*)(ws + o_pmu);
  float*    psig  = (float*)(ws + o_psig);
  float*    phat  = (float*)(ws + o_phat);
  float*    logp  = (float*)(ws + o_logp);
  uint32_t* keys  = (uint32_t*)(ws + o_keys);
  int*      aidx  = (int*)(ws + o_aidx);
  int*      nidx  = (int*)(ws + o_nidx);
  float*    ghat  = (float*)(ws + o_ghat);

  hipMemsetAsync(ws + o_gAB, 0, (size_t)2 * S_ * C_ * 4, stream);
  hipMemsetAsync(d_out, 0, (size_t)out_size * 4, stream);

  k_keys<<<1, 64, 0, stream>>>(keys);
  k_classify<<<256, 256, 0, stream>>>(label, mask, prob, cls, hrd);
  k_pack<<<dim3(P_ / 64, C_ / 64), 256, 0, stream>>>(mu, sg, pairp);
  k_count<<<256, 256, 0, stream>>>(cls, hrd, bcv, bch);
  k_scan<<<1, 64, 0, stream>>>(bcv, bch, bov, boh, cntv, cnth, basev, baseh);
  k_fill<<<256, 256, 0, stream>>>(cls, hrd, bov, boh, basev, baseh, posv, posh);
  k_sums<<<256, 256, 0, stream>>>(mu, sg, cls, gA, gB);
  k_proto<<<S_, 256, 0, stream>>>(gA, gB, mmu, msg, pmu, psig, phat);
  k_simlogp<<<S_, 64, 0, stream>>>(phat, psig, logp);
  k_anchors<<<S_, 256, 0, stream>>>(keys, cnth, baseh, posh, aidx);
  k_gen<<<dim3(GENV_, S_), 256, 0, stream>>>(keys, pmu, psig, ghat);
  k_sample<<<dim3(512, S_), 256, 0, stream>>>(keys, logp, cntv, basev, posv, nidx);
  k_main<<<(S_ * Q_) / 4, 256, 0, stream>>>(pairp, phat, psig, ghat, aidx, nidx, (float*)d_out);
}

// Round 2
// 1107.826 us; speedup vs baseline: 1.2663x; 1.2663x over previous
//
#include <hip/hip_runtime.h>
#include <hip/hip_fp16.h>
#include <cstdint>

#define B_   4
#define S_   19
#define HW_  16384
#define P_   65536
#define C_   256
#define Q_   256
#define NEG_ 512
#define NS_  131072
#define GENV_ 144

// ---------------- threefry2x32 (JAX-exact) ----------------
__device__ __forceinline__ void tf2x32(uint32_t k0, uint32_t k1, uint32_t x0, uint32_t x1,
                                       uint32_t& o0, uint32_t& o1) {
  uint32_t k2 = k0 ^ k1 ^ 0x1BD11BDAu;
#define TFR(r) { x0 += x1; x1 = (x1 << r) | (x1 >> (32 - r)); x1 ^= x0; }
  x0 += k0; x1 += k1;
  TFR(13) TFR(15) TFR(26) TFR(6)  x0 += k1; x1 += k2 + 1u;
  TFR(17) TFR(29) TFR(16) TFR(24) x0 += k2; x1 += k0 + 2u;
  TFR(13) TFR(15) TFR(26) TFR(6)  x0 += k0; x1 += k1 + 3u;
  TFR(17) TFR(29) TFR(16) TFR(24) x0 += k1; x1 += k2 + 4u;
  TFR(13) TFR(15) TFR(26) TFR(6)  x0 += k2; x1 += k0 + 5u;
#undef TFR
  o0 = x0; o1 = x1;
}

__device__ __forceinline__ uint32_t rbits(uint32_t k0, uint32_t k1, uint32_t n) {
  uint32_t a, b; tf2x32(k0, k1, 0u, n, a, b); return a ^ b;
}

__device__ __forceinline__ float bits2f01(uint32_t b) {
  return __uint_as_float((b >> 9) | 0x3f800000u) - 1.0f;
}

__device__ __forceinline__ float fastrcp(float x) {
  float r; asm("v_rcp_f32 %0, %1" : "=v"(r) : "v"(x)); return r;
}
__device__ __forceinline__ float fastrsq(float x) {
  float r; asm("v_rsq_f32 %0, %1" : "=v"(r) : "v"(x)); return r;
}

__device__ __forceinline__ float wred(float v) {
#pragma unroll
  for (int off = 32; off > 0; off >>= 1) v += __shfl_xor(v, off, 64);
  return v;
}
__device__ __forceinline__ void wred3(float& a, float& b, float& c) {
#pragma unroll
  for (int off = 32; off > 0; off >>= 1) {
    a += __shfl_xor(a, off, 64);
    b += __shfl_xor(b, off, 64);
    c += __shfl_xor(c, off, 64);
  }
}

__device__ __forceinline__ void lse_up(float lg, float& m, float& l) {
  if (lg > m) { l = l * __expf(m - lg) + 1.0f; m = lg; }
  else l += __expf(lg - m);
}
__device__ __forceinline__ void lse_merge(float& m, float& l, float mo, float lo) {
  float mn = fmaxf(m, mo);
  l = l * __expf(m - mn) + lo * __expf(mo - mn);
  m = mn;
}

// XLA ErfInv32 (Giles)
__device__ __forceinline__ float erfinv_f(float x) {
  float w = -__logf(fmaxf(fmaf(-x, x, 1.0f), 1e-37f));
  float p;
  if (w < 5.0f) {
    w -= 2.5f;
    p = 2.81022636e-08f;
    p = fmaf(p, w, 3.43273939e-07f);
    p = fmaf(p, w, -3.5233877e-06f);
    p = fmaf(p, w, -4.39150654e-06f);
    p = fmaf(p, w, 0.00021858087f);
    p = fmaf(p, w, -0.00125372503f);
    p = fmaf(p, w, -0.00417768164f);
    p = fmaf(p, w, 0.246640727f);
    p = fmaf(p, w, 1.50140941f);
  } else {
    w = sqrtf(w) - 3.0f;
    p = -0.000200214257f;
    p = fmaf(p, w, 0.000100950558f);
    p = fmaf(p, w, 0.00134934322f);
    p = fmaf(p, w, -0.00367342844f);
    p = fmaf(p, w, 0.00573950773f);
    p = fmaf(p, w, -0.0076224613f);
    p = fmaf(p, w, 0.00943887047f);
    p = fmaf(p, w, 1.00167406f);
    p = fmaf(p, w, 2.83297682f);
  }
  return p * x;
}

__device__ __forceinline__ void unp(uint32_t u, float& lo, float& hi) {
  __half2 h = *reinterpret_cast<__half2*>(&u);
  lo = __low2float(h); hi = __high2float(h);
}

// ---------------- K0: per-class keys ----------------
__global__ void k_keys(uint32_t* __restrict__ keys) {
  int i = threadIdx.x;
  if (i >= S_) return;
  uint32_t f0, f1;
  tf2x32(0u, 1234u, 0u, (uint32_t)i, f0, f1);
#pragma unroll
  for (int t = 0; t < 4; ++t) {
    uint32_t a, b;
    tf2x32(f0, f1, 0u, (uint32_t)t, a, b);
    keys[i * 8 + t * 2] = a; keys[i * 8 + t * 2 + 1] = b;
  }
}

// ---------------- K1: class id + hard flag ----------------
__global__ __launch_bounds__(256) void k_classify(const float* __restrict__ label,
    const float* __restrict__ mask, const float* __restrict__ prob,
    int* __restrict__ cls, int* __restrict__ hrd) {
  int p = blockIdx.x * 256 + threadIdx.x;
  int b = p >> 14, rem = p & (HW_ - 1);
  int sp = -1;
#pragma unroll
  for (int s = 0; s < S_; ++s) {
    float l = label[((b * S_ + s) << 14) + rem];
    if (l > 0.5f) sp = s;
  }
  if (mask[(b << 14) + rem] <= 0.5f) sp = -1;
  int h = 0;
  if (sp >= 0) h = (prob[((b * S_ + sp) << 14) + rem] < 0.97f) ? 1 : 0;
  cls[p] = sp; hrd[p] = h;
}

// ---------------- K1b: pack (B,C,H,W) -> (P,C) half2 ----------------
__global__ __launch_bounds__(256) void k_pack(const float* __restrict__ mu,
    const float* __restrict__ sg, __half2* __restrict__ pair) {
  __shared__ float smu[64][65];
  __shared__ float ssg[64][65];
  int p0 = blockIdx.x * 64;
  int c0 = blockIdx.y * 64;
  int b = p0 >> 14; int rem0 = p0 & (HW_ - 1);
  int px = threadIdx.x & 63, cy = threadIdx.x >> 6;
#pragma unroll
  for (int it = 0; it < 16; ++it) {
    int cl = cy + it * 4;
    int addr = ((b * C_ + c0 + cl) << 14) + rem0 + px;
    smu[cl][px] = mu[addr];
    ssg[cl][px] = sg[addr];
  }
  __syncthreads();
  int cx = threadIdx.x & 63, py = threadIdx.x >> 6;
#pragma unroll
  for (int it = 0; it < 16; ++it) {
    int pl = py + it * 4;
    int p = p0 + pl;
    pair[(size_t)p * C_ + c0 + cx] = __floats2half2_rn(smu[cx][pl], ssg[cx][pl]);
  }
}

// ---------------- K2: ordered per-class pixel lists ----------------
__global__ __launch_bounds__(256) void k_count(const int* __restrict__ cls, const int* __restrict__ hrd,
    int* __restrict__ bcv, int* __restrict__ bch) {
  __shared__ int hv[S_], hh[S_];
  int t = threadIdx.x;
  if (t < S_) { hv[t] = 0; hh[t] = 0; }
  __syncthreads();
  int p = blockIdx.x * 256 + t;
  int s = cls[p];
  if (s >= 0) { atomicAdd(&hv[s], 1); if (hrd[p]) atomicAdd(&hh[s], 1); }
  __syncthreads();
  if (t < S_) { bcv[t * 256 + blockIdx.x] = hv[t]; bch[t * 256 + blockIdx.x] = hh[t]; }
}

__global__ __launch_bounds__(64) void k_scan(int* __restrict__ bcv, int* __restrict__ bch,
    int* __restrict__ bov, int* __restrict__ boh,
    int* __restrict__ cntv, int* __restrict__ cnth,
    int* __restrict__ basev, int* __restrict__ baseh) {
  int s = threadIdx.x;
  if (s < S_) {
    int run = 0;
    for (int b = 0; b < 256; ++b) { int v = bcv[s * 256 + b]; bov[s * 256 + b] = run; run += v; }
    cntv[s] = run;
    run = 0;
    for (int b = 0; b < 256; ++b) { int v = bch[s * 256 + b]; boh[s * 256 + b] = run; run += v; }
    cnth[s] = run;
  }
  __syncthreads();
  if (s == 0) {
    int bv = 0, bh = 0;
    for (int k = 0; k < S_; ++k) { basev[k] = bv; bv += cntv[k]; baseh[k] = bh; bh += cnth[k]; }
  }
}

__global__ __launch_bounds__(256) void k_fill(const int* __restrict__ cls, const int* __restrict__ hrd,
    const int* __restrict__ bov, const int* __restrict__ boh,
    const int* __restrict__ basev, const int* __restrict__ baseh,
    int* __restrict__ posv, int* __restrict__ posh) {
  __shared__ int lc[256], lh[256];
  int t = threadIdx.x;
  int p = blockIdx.x * 256 + t;
  int s = cls[p]; int h = hrd[p];
  lc[t] = s; lh[t] = h;
  __syncthreads();
  if (s >= 0) {
    int rv = 0, rh = 0;
    for (int k = 0; k < t; ++k) { if (lc[k] == s) { rv++; rh += lh[k]; } }
    posv[basev[s] + bov[s * 256 + blockIdx.x] + rv] = p;
    if (h) posh[baseh[s] + boh[s * 256 + blockIdx.x] + rh] = p;
  }
}

// ---------------- K3: per-class sums ----------------
__global__ __launch_bounds__(256) void k_sums(const float* __restrict__ mu, const float* __restrict__ sg,
    const int* __restrict__ cls, float* __restrict__ gA, float* __restrict__ gB) {
  __shared__ float accA[S_][C_];
  __shared__ float accB[S_][C_];
  int t = threadIdx.x;
  for (int e = t; e < S_ * C_; e += 256) { (&accA[0][0])[e] = 0.f; (&accB[0][0])[e] = 0.f; }
  __syncthreads();
  int p = blockIdx.x * 256 + t;
  int b = p >> 14, rem = p & (HW_ - 1);
  int s = cls[p];
  if (s >= 0) {
    size_t base = ((size_t)(b * C_) << 14) + rem;
    for (int c = 0; c < C_; ++c) {
      float sv = sg[base + ((size_t)c << 14)];
      float mv = mu[base + ((size_t)c << 14)];
      float ia = 1.0f / sv;
      atomicAdd(&accA[s][c], ia);
      atomicAdd(&accB[s][c], ia * mv);
    }
  }
  __syncthreads();
  for (int e = t; e < S_ * C_; e += 256) {
    atomicAdd(&gA[e], (&accA[0][0])[e]);
    atomicAdd(&gB[e], (&accB[0][0])[e]);
  }
}

// ---------------- K4: prototypes ----------------
__global__ __launch_bounds__(256) void k_proto(const float* __restrict__ gA, const float* __restrict__ gB,
    const float* __restrict__ mmu, const float* __restrict__ msg,
    float* __restrict__ pmu, float* __restrict__ psig, float* __restrict__ phat) {
  int s = blockIdx.x, c = threadIdx.x;
  int e = s * C_ + c;
  float A = gA[e], Bv = gB[e];
  float psb = 1.0f / A;
  float pmb = psb * Bv;
  float ms = msg[e], mm = mmu[e];
  float ps = 1.0f / (1.0f / psb + 1.0f / ms);
  float pm = ps * (mm / ms + pmb / psb);
  pmu[e] = pm; psig[e] = ps;
  __shared__ float red[4];
  float w = wred(pm * pm);
  int lane = c & 63, wv = c >> 6;
  if (lane == 0) red[wv] = w;
  __syncthreads();
  float tot = red[0] + red[1] + red[2] + red[3];
  float nrm = fmaxf(sqrtf(tot), 1e-12f);
  phat[e] = pm / nrm;
}

// ---------------- K5a: sim -> log_softmax ----------------
__global__ __launch_bounds__(64) void k_simlogp(const float* __restrict__ phat,
    const float* __restrict__ psig, float* __restrict__ logp) {
  int i = blockIdx.x, lane = threadIdx.x;
  int c0 = lane * 4;
  float phi[4], psi[4];
#pragma unroll
  for (int k = 0; k < 4; ++k) { phi[k] = phat[i * C_ + c0 + k]; psi[k] = psig[i * C_ + c0 + k]; }
  float xs[18];
#pragma unroll
  for (int j = 0; j < 18; ++j) {
    int o = i + 1 + j; if (o >= S_) o -= S_;
    float t = 0.f;
#pragma unroll
    for (int k = 0; k < 4; ++k) {
      float d = phi[k] - phat[o * C_ + c0 + k];
      float dn = psi[k] + psig[o * C_ + c0 + k];
      t += d * d / dn + logf(dn);
    }
    t = wred(t);
    xs[j] = (-0.5f * t * (1.0f / 256.0f)) * 2.0f;
  }
  float m = xs[0];
#pragma unroll
  for (int j = 1; j < 18; ++j) m = fmaxf(m, xs[j]);
  float se = 0.f;
#pragma unroll
  for (int j = 0; j < 18; ++j) se += expf(xs[j] - m);
  float lg = logf(se);
  if (lane == 0) {
#pragma unroll
    for (int j = 0; j < 18; ++j) logp[i * 18 + j] = xs[j] - m - lg;
  }
}

// ---------------- K5d: anchors ----------------
__global__ __launch_bounds__(256) void k_anchors(const uint32_t* __restrict__ keys,
    const int* __restrict__ cnth, const int* __restrict__ baseh,
    const int* __restrict__ posh, int* __restrict__ aidx) {
  int i = blockIdx.x, q = threadIdx.x;
  uint32_t k0 = keys[i * 8 + 0], k1 = keys[i * 8 + 1];
  float u = bits2f01(rbits(k0, k1, (uint32_t)q));
  int cnt = cnth[i];
  int idx = P_ - 1;
  if (cnt > 0) {
    int kk = (int)(u * (float)cnt);
    if (kk >= cnt) kk = cnt - 1;
    idx = posh[baseh[i] + kk];
  }
  aidx[i * Q_ + q] = idx;
}

// ---------------- K5c: generalized prototypes ----------------
__global__ __launch_bounds__(256) void k_gen(const uint32_t* __restrict__ keys,
    const float* __restrict__ pmu, const float* __restrict__ psig, float* __restrict__ ghat) {
  int v = blockIdx.x, i = blockIdx.y, c = threadIdx.x;
  int o = i + 1 + (v >> 3); if (o >= S_) o -= S_;
  uint32_t k0 = keys[i * 8 + 6], k1 = keys[i * 8 + 7];
  uint32_t bits = rbits(k0, k1, (uint32_t)(v * C_ + c));
  float f01 = bits2f01(bits);
  const float lo = -0.99999994f;
  float u = fmaxf(f01 * 2.0f + lo, lo);
  float eps = 1.41421356237f * erfinv_f(u);
  float g = pmu[o * C_ + c] + sqrtf(psig[o * C_ + c]) * eps;
  __shared__ float red[4];
  float w = wred(g * g);
  int lane = c & 63, wv = c >> 6;
  if (lane == 0) red[wv] = w;
  __syncthreads();
  float tot = red[0] + red[1] + red[2] + red[3];
  float nrm = fmaxf(sqrtf(tot), 1e-12f);
  ghat[((size_t)(i * GENV_ + v)) * C_ + c] = g / nrm;
}

// ---------------- K5b: class + negative sampling ----------------
__global__ __launch_bounds__(256) void k_sample(const uint32_t* __restrict__ keys,
    const float* __restrict__ logp, const int* __restrict__ cntv, const int* __restrict__ basev,
    const int* __restrict__ posv, int* __restrict__ nidx) {
  int i = blockIdx.y;
  int m = blockIdx.x * 256 + threadIdx.x;
  __shared__ float lp[18];
  __shared__ int lcnt[S_], lbase[S_];
  int t = threadIdx.x;
  if (t < 18) lp[t] = logp[i * 18 + t];
  if (t < S_) { lcnt[t] = cntv[t]; lbase[t] = basev[t]; }
  __syncthreads();
  uint32_t kc0 = keys[i * 8 + 2], kc1 = keys[i * 8 + 3];
  uint32_t kn0 = keys[i * 8 + 4], kn1 = keys[i * 8 + 5];
  float bv = -1e30f; int best = 0;
  for (int s = 0; s < 18; ++s) {
    uint32_t b = rbits(kc0, kc1, (uint32_t)m * 18u + (uint32_t)s);
    float u = fmaxf(bits2f01(b), 1.17549435e-38f);
    float g = -__logf(-__logf(u)) + lp[s];
    if (g > bv) { bv = g; best = s; }
  }
  float un = bits2f01(rbits(kn0, kn1, (uint32_t)m));
  int cc = i + 1 + best; if (cc >= S_) cc -= S_;
  int cnt = lcnt[cc];
  int idx = P_ - 1;
  if (cnt > 0) {
    int kk = (int)(un * (float)cnt);
    if (kk >= cnt) kk = cnt - 1;
    idx = posv[lbase[cc] + kk];
  }
  nidx[(size_t)i * NS_ + m] = idx;
}

// ---------------- K6: main — one BLOCK per anchor; lane-per-negative streaming ----------------
__global__ __launch_bounds__(256, 4) void k_main(const __half2* __restrict__ pair,
    const float* __restrict__ phat, const float* __restrict__ psig,
    const float* __restrict__ ghat, const int* __restrict__ aidx,
    const int* __restrict__ nidx, float* __restrict__ out) {
  __shared__ float2 ancA[C_];   // {ahat, asg}
  __shared__ float2 ancG[C_];   // {w, ahat*w}
  __shared__ float redS[4];
  __shared__ float redm[3][4];
  __shared__ float2 mlw[4];

  int bid = blockIdx.x;
  int i = bid >> 8, q = bid & 255;
  int t = threadIdx.x, w = t >> 6, lane = t & 63;

  // ---- prep: anchor channel t ----
  int ap = aidx[bid];
  __half2 ah = pair[(size_t)ap * C_ + t];
  float amu = __low2float(ah), asg = __high2float(ah);
  float s2 = amu * amu;
  s2 = wred(s2);
  if (lane == 0) redS[w] = s2;
  __syncthreads();
  float tot = redS[0] + redS[1] + redS[2] + redS[3];
  float rn = 1.0f / fmaxf(sqrtf(tot), 1e-12f);
  float ahat = amu * rn;
  float wv = fastrcp(asg);
  ancA[t] = make_float2(ahat, asg);
  ancG[t] = make_float2(wv, ahat * wv);

  float pm = phat[i * C_ + t];
  float ps = psig[i * C_ + t];
  float dnp = asg + ps;
  float dd = ahat - pm;
  float post = fmaf(dd * dd, fastrcp(dnp), __logf(dnp));
  float a1t = ahat * ahat * wv;
  float lat = __logf(asg);
  wred3(post, a1t, lat);
  if (lane == 0) { redm[0][w] = post; redm[1][w] = a1t; redm[2][w] = lat; }
  __syncthreads();
  float postS = redm[0][0] + redm[0][1] + redm[0][2] + redm[0][3];
  float Kc = (redm[1][0] + redm[1][1] + redm[1][2] + redm[1][3])
           + (redm[2][0] + redm[2][1] + redm[2][2] + redm[2][3]);
  float logit0 = -postS * (1.0f / 256.0f);

  // ---- negatives: lane owns rows j1, j2 ----
  const int* nrow = nidx + (size_t)i * NS_ + (size_t)q * NEG_;
  int j1 = w * 128 + lane;
  const uint4* rA = (const uint4*)(pair + (size_t)nrow[j1] * C_);
  const uint4* rB = (const uint4*)(pair + (size_t)nrow[j1 + 64] * C_);
  const float4* ancAf = (const float4*)ancA;
  const float4* ancGf = (const float4*)ancG;

  float sA1 = 0.f, sC1 = 0.f, sNR1 = 0.f, sN1 = 0.f, sL1 = 0.f;
  float sA2 = 0.f, sC2 = 0.f, sNR2 = 0.f, sN2 = 0.f, sL2 = 0.f;
  uint4 cA0 = rA[0], cA1 = rA[1], cB0 = rB[0], cB1 = rB[1];

  for (int it = 0; it < 32; ++it) {
    int nx = ((it + 1) & 31) << 1;
    uint4 pA0 = rA[nx], pA1 = rA[nx + 1], pB0 = rB[nx], pB1 = rB[nx + 1];
    float4 an0 = ancAf[it * 4 + 0];
    float4 an1 = ancAf[it * 4 + 1];
    float4 an2 = ancAf[it * 4 + 2];
    float4 an3 = ancAf[it * 4 + 3];
    uint32_t da[8] = {cA0.x, cA0.y, cA0.z, cA0.w, cA1.x, cA1.y, cA1.z, cA1.w};
    uint32_t db[8] = {cB0.x, cB0.y, cB0.z, cB0.w, cB1.x, cB1.y, cB1.z, cB1.w};
    float anc[16] = {an0.x, an0.y, an0.z, an0.w, an1.x, an1.y, an1.z, an1.w,
                     an2.x, an2.y, an2.z, an2.w, an3.x, an3.y, an3.z, an3.w};
    float pr1 = 1.0f, pr2 = 1.0f;
#pragma unroll
    for (int k = 0; k < 8; ++k) {
      float ahc = anc[2 * k], asc = anc[2 * k + 1];
      float ah2 = ahc * ahc;
      float nm1, ns1, nm2, ns2;
      unp(da[k], nm1, ns1); unp(db[k], nm2, ns2);
      float dn1 = asc + ns1, dn2 = asc + ns2;
      float r1 = fastrcp(dn1), r2 = fastrcp(dn2);
      pr1 *= dn1; pr2 *= dn2;
      sA1 = fmaf(ah2, r1, sA1);      sA2 = fmaf(ah2, r2, sA2);
      float q1 = nm1 * r1, q2 = nm2 * r2;
      sC1 = fmaf(ahc, q1, sC1);      sC2 = fmaf(ahc, q2, sC2);
      sNR1 = fmaf(nm1, q1, sNR1);    sNR2 = fmaf(nm2, q2, sNR2);
      sN1 = fmaf(nm1, nm1, sN1);     sN2 = fmaf(nm2, nm2, sN2);
    }
    sL1 += __logf(pr1); sL2 += __logf(pr2);
    cA0 = pA0; cA1 = pA1; cB0 = pB0; cB1 = pB1;
  }

  float m = -1e30f, l = 0.0f;
  {
    float rn1 = fastrsq(sN1);
    float tt = sA1 + (rn1 * rn1) * sNR1 - 2.0f * rn1 * sC1 + sL1;
    lse_up(-tt * (1.0f / 256.0f), m, l);
    float rn2 = fastrsq(sN2);
    float t2 = sA2 + (rn2 * rn2) * sNR2 - 2.0f * rn2 * sC2 + sL2;
    lse_up(-t2 * (1.0f / 256.0f), m, l);
  }

  // ---- gens: 36 per wave, lanes 0..35 ----
  if (lane < 36) {
    int g = lane * 4 + w;  // bijective onto 0..143
    const float4* gp = (const float4*)(ghat + ((size_t)(i * GENV_ + g)) * C_);
    float a1 = 0.f, a2 = 0.f;
    for (int it = 0; it < 64; ++it) {
      float4 gv = gp[it];
      float4 g01 = ancGf[it * 2];
      float4 g23 = ancGf[it * 2 + 1];
      a1 = fmaf(gv.x * gv.x, g01.x, a1); a2 = fmaf(gv.x, g01.y, a2);
      a1 = fmaf(gv.y * gv.y, g01.z, a1); a2 = fmaf(gv.y, g01.w, a2);
      a1 = fmaf(gv.z * gv.z, g23.x, a1); a2 = fmaf(gv.z, g23.y, a2);
      a1 = fmaf(gv.w * gv.w, g23.z, a1); a2 = fmaf(gv.w, g23.w, a2);
    }
    float lg = -(Kc + a1 - 2.0f * a2) * (1.0f / 256.0f);
    lse_up(lg, m, l);
  }

  // ---- merge LSE: wave butterfly, then across waves ----
#pragma unroll
  for (int off = 32; off > 0; off >>= 1) {
    float mo = __shfl_xor(m, off, 64);
    float lo = __shfl_xor(l, off, 64);
    lse_merge(m, l, mo, lo);
  }
  if (lane == 0) mlw[w] = make_float2(m, l);
  __syncthreads();
  if (t == 0) {
    float mm = mlw[0].x, ll = mlw[0].y;
    lse_merge(mm, ll, mlw[1].x, mlw[1].y);
    lse_merge(mm, ll, mlw[2].x, mlw[2].y);
    lse_merge(mm, ll, mlw[3].x, mlw[3].y);
    lse_merge(mm, ll, logit0, 1.0f);
    float lse = mm + __logf(ll);
    float contrib = logit0 - lse;
    atomicAdd(out, -contrib * (1.0f / (19.0f * 256.0f)));
  }
}

// ---------------- host ----------------
extern "C" void kernel_launch(void* const* d_in, const int* in_sizes, int n_in,
                              void* d_out, int out_size, void* d_ws, size_t ws_size,
                              hipStream_t stream) {
  const float* mu    = (const float*)d_in[0];
  const float* sg    = (const float*)d_in[1];
  const float* label = (const float*)d_in[2];
  const float* mask  = (const float*)d_in[3];
  const float* prob  = (const float*)d_in[4];
  const float* mmu   = (const float*)d_in[5];
  const float* msg   = (const float*)d_in[6];

  char* ws = (char*)d_ws;
  size_t off = 0;
  auto take = [&](size_t bytes) { size_t r = off; off = (off + bytes + 255) & ~(size_t)255; return r; };
  size_t o_pair  = take((size_t)P_ * C_ * 4);
  size_t o_cls   = take((size_t)P_ * 4);
  size_t o_hrd   = take((size_t)P_ * 4);
  size_t o_bcv   = take(S_ * 256 * 4);
  size_t o_bch   = take(S_ * 256 * 4);
  size_t o_bov   = take(S_ * 256 * 4);
  size_t o_boh   = take(S_ * 256 * 4);
  size_t o_cntv  = take(S_ * 4);
  size_t o_cnth  = take(S_ * 4);
  size_t o_basev = take(S_ * 4);
  size_t o_baseh = take(S_ * 4);
  size_t o_posv  = take((size_t)P_ * 4);
  size_t o_posh  = take((size_t)P_ * 4);
  size_t o_gAB   = take((size_t)2 * S_ * C_ * 4);
  size_t o_pmu   = take(S_ * C_ * 4);
  size_t o_psig  = take(S_ * C_ * 4);
  size_t o_phat  = take(S_ * C_ * 4);
  size_t o_logp  = take(S_ * 18 * 4);
  size_t o_keys  = take(S_ * 8 * 4);
  size_t o_aidx  = take(S_ * Q_ * 4);
  size_t o_nidx  = take((size_t)S_ * NS_ * 4);
  size_t o_ghat  = take((size_t)S_ * GENV_ * C_ * 4);
  if (ws_size < off) return;

  __half2*  pairp = (__half2*)(ws + o_pair);
  int*      cls   = (int*)(ws + o_cls);
  int*      hrd   = (int*)(ws + o_hrd);
  int*      bcv   = (int*)(ws + o_bcv);
  int*      bch   = (int*)(ws + o_bch);
  int*      bov   = (int*)(ws + o_bov);
  int*      boh   = (int*)(ws + o_boh);
  int*      cntv  = (int*)(ws + o_cntv);
  int*      cnth  = (int*)(ws + o_cnth);
  int*      basev = (int*)(ws + o_basev);
  int*      baseh = (int*)(ws + o_baseh);
  int*      posv  = (int*)(ws + o_posv);
  int*      posh  = (int*)(ws + o_posh);
  float*    gA    = (float*)(ws + o_gAB);
  float*    gB    = gA + S_ * C_;
  float*    pmu   = (float*)(ws + o_pmu);
  float*    psig  = (float*)(ws + o_psig);
  float*    phat  = (float*)(ws + o_phat);
  float*    logp  = (float*)(ws + o_logp);
  uint32_t* keys  = (uint32_t*)(ws + o_keys);
  int*      aidx  = (int*)(ws + o_aidx);
  int*      nidx  = (int*)(ws + o_nidx);
  float*    ghat  = (float*)(ws + o_ghat);

  hipMemsetAsync(ws + o_gAB, 0, (size_t)2 * S_ * C_ * 4, stream);
  hipMemsetAsync(d_out, 0, (size_t)out_size * 4, stream);

  k_keys<<<1, 64, 0, stream>>>(keys);
  k_classify<<<256, 256, 0, stream>>>(label, mask, prob, cls, hrd);
  k_pack<<<dim3(P_ / 64, C_ / 64), 256, 0, stream>>>(mu, sg, pairp);
  k_count<<<256, 256, 0, stream>>>(cls, hrd, bcv, bch);
  k_scan<<<1, 64, 0, stream>>>(bcv, bch, bov, boh, cntv, cnth, basev, baseh);
  k_fill<<<256, 256, 0, stream>>>(cls, hrd, bov, boh, basev, baseh, posv, posh);
  k_sums<<<256, 256, 0, stream>>>(mu, sg, cls, gA, gB);
  k_proto<<<S_, 256, 0, stream>>>(gA, gB, mmu, msg, pmu, psig, phat);
  k_simlogp<<<S_, 64, 0, stream>>>(phat, psig, logp);
  k_anchors<<<S_, 256, 0, stream>>>(keys, cnth, baseh, posh, aidx);
  k_gen<<<dim3(GENV_, S_), 256, 0, stream>>>(keys, pmu, psig, ghat);
  k_sample<<<dim3(512, S_), 256, 0, stream>>>(keys, logp, cntv, basev, posv, nidx);
  k_main<<<S_ * Q_, 256, 0, stream>>>(pairp, phat, psig, ghat, aidx, nidx, (float*)d_out);
}

// Round 3
// 924.795 us; speedup vs baseline: 1.5170x; 1.1979x over previous
//
#include <hip/hip_runtime.h>
#include <hip/hip_fp16.h>
#include <hip/hip_fp8.h>
#include <cstdint>

#define B_   4
#define S_   19
#define HW_  16384
#define P_   65536
#define C_   256
#define Q_   256
#define NEG_ 512
#define NS_  131072
#define GENV_ 144

typedef float v2f __attribute__((ext_vector_type(2)));

#if __has_builtin(__builtin_amdgcn_cvt_pk_f32_fp8) && __has_builtin(__builtin_amdgcn_cvt_pk_fp8_f32)
#define HAVE_HW_FP8 1
#endif

template<int W> __device__ __forceinline__ v2f cvt8(uint32_t d) {
#ifdef HAVE_HW_FP8
  v2f r = __builtin_amdgcn_cvt_pk_f32_fp8((int)d, W);
  return r;
#else
  __hip_fp8_e4m3 h0, h1;
  h0.__x = (uint8_t)(d >> (W * 16));
  h1.__x = (uint8_t)(d >> (W * 16 + 8));
  v2f r; r.x = (float)h0; r.y = (float)h1; return r;
#endif
}
template<int W> __device__ __forceinline__ uint32_t pk8(float a, float b, uint32_t old) {
#ifdef HAVE_HW_FP8
  return (uint32_t)__builtin_amdgcn_cvt_pk_fp8_f32(a, b, (int)old, W);
#else
  __hip_fp8_e4m3 ha(a), hb(b);
  uint32_t v = (uint32_t)ha.__x | ((uint32_t)hb.__x << 8);
  return (old & (W ? 0x0000FFFFu : 0xFFFF0000u)) | (v << (W * 16));
#endif
}

// ---------------- threefry2x32 (JAX-exact) ----------------
__device__ __forceinline__ void tf2x32(uint32_t k0, uint32_t k1, uint32_t x0, uint32_t x1,
                                       uint32_t& o0, uint32_t& o1) {
  uint32_t k2 = k0 ^ k1 ^ 0x1BD11BDAu;
#define TFR(r) { x0 += x1; x1 = (x1 << r) | (x1 >> (32 - r)); x1 ^= x0; }
  x0 += k0; x1 += k1;
  TFR(13) TFR(15) TFR(26) TFR(6)  x0 += k1; x1 += k2 + 1u;
  TFR(17) TFR(29) TFR(16) TFR(24) x0 += k2; x1 += k0 + 2u;
  TFR(13) TFR(15) TFR(26) TFR(6)  x0 += k0; x1 += k1 + 3u;
  TFR(17) TFR(29) TFR(16) TFR(24) x0 += k1; x1 += k2 + 4u;
  TFR(13) TFR(15) TFR(26) TFR(6)  x0 += k2; x1 += k0 + 5u;
#undef TFR
  o0 = x0; o1 = x1;
}

__device__ __forceinline__ uint32_t rbits(uint32_t k0, uint32_t k1, uint32_t n) {
  uint32_t a, b; tf2x32(k0, k1, 0u, n, a, b); return a ^ b;
}

__device__ __forceinline__ float bits2f01(uint32_t b) {
  return __uint_as_float((b >> 9) | 0x3f800000u) - 1.0f;
}

__device__ __forceinline__ float fastrcp(float x) {
  float r; asm("v_rcp_f32 %0, %1" : "=v"(r) : "v"(x)); return r;
}
__device__ __forceinline__ float fastrsq(float x) {
  float r; asm("v_rsq_f32 %0, %1" : "=v"(r) : "v"(x)); return r;
}

__device__ __forceinline__ float wred(float v) {
#pragma unroll
  for (int off = 32; off > 0; off >>= 1) v += __shfl_xor(v, off, 64);
  return v;
}
__device__ __forceinline__ void wred3(float& a, float& b, float& c) {
#pragma unroll
  for (int off = 32; off > 0; off >>= 1) {
    a += __shfl_xor(a, off, 64);
    b += __shfl_xor(b, off, 64);
    c += __shfl_xor(c, off, 64);
  }
}

__device__ __forceinline__ void lse_up(float lg, float& m, float& l) {
  if (lg > m) { l = l * __expf(m - lg) + 1.0f; m = lg; }
  else l += __expf(lg - m);
}
__device__ __forceinline__ void lse_merge(float& m, float& l, float mo, float lo) {
  float mn = fmaxf(m, mo);
  l = l * __expf(m - mn) + lo * __expf(mo - mn);
  m = mn;
}

// XLA ErfInv32 (Giles)
__device__ __forceinline__ float erfinv_f(float x) {
  float w = -__logf(fmaxf(fmaf(-x, x, 1.0f), 1e-37f));
  float p;
  if (w < 5.0f) {
    w -= 2.5f;
    p = 2.81022636e-08f;
    p = fmaf(p, w, 3.43273939e-07f);
    p = fmaf(p, w, -3.5233877e-06f);
    p = fmaf(p, w, -4.39150654e-06f);
    p = fmaf(p, w, 0.00021858087f);
    p = fmaf(p, w, -0.00125372503f);
    p = fmaf(p, w, -0.00417768164f);
    p = fmaf(p, w, 0.246640727f);
    p = fmaf(p, w, 1.50140941f);
  } else {
    w = sqrtf(w) - 3.0f;
    p = -0.000200214257f;
    p = fmaf(p, w, 0.000100950558f);
    p = fmaf(p, w, 0.00134934322f);
    p = fmaf(p, w, -0.00367342844f);
    p = fmaf(p, w, 0.00573950773f);
    p = fmaf(p, w, -0.0076224613f);
    p = fmaf(p, w, 0.00943887047f);
    p = fmaf(p, w, 1.00167406f);
    p = fmaf(p, w, 2.83297682f);
  }
  return p * x;
}

// ---------------- K0: per-class keys ----------------
__global__ void k_keys(uint32_t* __restrict__ keys) {
  int i = threadIdx.x;
  if (i >= S_) return;
  uint32_t f0, f1;
  tf2x32(0u, 1234u, 0u, (uint32_t)i, f0, f1);
#pragma unroll
  for (int t = 0; t < 4; ++t) {
    uint32_t a, b;
    tf2x32(f0, f1, 0u, (uint32_t)t, a, b);
    keys[i * 8 + t * 2] = a; keys[i * 8 + t * 2 + 1] = b;
  }
}

// ---------------- K1: class id + hard flag ----------------
__global__ __launch_bounds__(256) void k_classify(const float* __restrict__ label,
    const float* __restrict__ mask, const float* __restrict__ prob,
    int* __restrict__ cls, int* __restrict__ hrd) {
  int p = blockIdx.x * 256 + threadIdx.x;
  int b = p >> 14, rem = p & (HW_ - 1);
  int sp = -1;
#pragma unroll
  for (int s = 0; s < S_; ++s) {
    float l = label[((b * S_ + s) << 14) + rem];
    if (l > 0.5f) sp = s;
  }
  if (mask[(b << 14) + rem] <= 0.5f) sp = -1;
  int h = 0;
  if (sp >= 0) h = (prob[((b * S_ + sp) << 14) + rem] < 0.97f) ? 1 : 0;
  cls[p] = sp; hrd[p] = h;
}

// ---------------- K1b: pack (B,C,H,W) f32 -> (P,C) fp8 pair + norm2 ----------------
__global__ __launch_bounds__(256) void k_pack(const float* __restrict__ mu,
    const float* __restrict__ sg, uint32_t* __restrict__ pair8, float* __restrict__ norm2) {
  __shared__ float smu[64][65];
  __shared__ float ssg[64][65];
  int p0 = blockIdx.x * 64, c0 = blockIdx.y * 64;
  int b = p0 >> 14, rem0 = p0 & (HW_ - 1);
  int px = threadIdx.x & 63, cy = threadIdx.x >> 6;
#pragma unroll
  for (int itr = 0; itr < 16; ++itr) {
    int cl = cy + itr * 4;
    int addr = ((b * C_ + c0 + cl) << 14) + rem0 + px;
    smu[cl][px] = mu[addr];
    ssg[cl][px] = sg[addr];
  }
  __syncthreads();
#pragma unroll
  for (int itr = 0; itr < 8; ++itr) {
    int e = itr * 256 + threadIdx.x;
    int pxl = e >> 5, dw = e & 31, cl = dw * 2;
    uint32_t wd = pk8<0>(smu[cl][pxl], ssg[cl][pxl], 0u);
    wd = pk8<1>(smu[cl + 1][pxl], ssg[cl + 1][pxl], wd);
    pair8[(size_t)(p0 + pxl) * 128 + (c0 >> 1) + dw] = wd;
  }
  int pxn = threadIdx.x >> 2, qn = threadIdx.x & 3;
  float s2 = 0.f;
#pragma unroll
  for (int k = 0; k < 16; ++k) { float v = smu[qn * 16 + k][pxn]; s2 = fmaf(v, v, s2); }
  s2 += __shfl_xor(s2, 1, 64);
  s2 += __shfl_xor(s2, 2, 64);
  if (qn == 0) atomicAdd(&norm2[p0 + pxn], s2);
}

// ---------------- K2: ordered per-class pixel lists ----------------
__global__ __launch_bounds__(256) void k_count(const int* __restrict__ cls, const int* __restrict__ hrd,
    int* __restrict__ bcv, int* __restrict__ bch) {
  __shared__ int hv[S_], hh[S_];
  int t = threadIdx.x;
  if (t < S_) { hv[t] = 0; hh[t] = 0; }
  __syncthreads();
  int p = blockIdx.x * 256 + t;
  int s = cls[p];
  if (s >= 0) { atomicAdd(&hv[s], 1); if (hrd[p]) atomicAdd(&hh[s], 1); }
  __syncthreads();
  if (t < S_) { bcv[t * 256 + blockIdx.x] = hv[t]; bch[t * 256 + blockIdx.x] = hh[t]; }
}

__global__ __launch_bounds__(64) void k_scan(int* __restrict__ bcv, int* __restrict__ bch,
    int* __restrict__ bov, int* __restrict__ boh,
    int* __restrict__ cntv, int* __restrict__ cnth,
    int* __restrict__ basev, int* __restrict__ baseh) {
  int s = threadIdx.x;
  if (s < S_) {
    int run = 0;
    for (int b = 0; b < 256; ++b) { int v = bcv[s * 256 + b]; bov[s * 256 + b] = run; run += v; }
    cntv[s] = run;
    run = 0;
    for (int b = 0; b < 256; ++b) { int v = bch[s * 256 + b]; boh[s * 256 + b] = run; run += v; }
    cnth[s] = run;
  }
  __syncthreads();
  if (s == 0) {
    int bv = 0, bh = 0;
    for (int k = 0; k < S_; ++k) { basev[k] = bv; bv += cntv[k]; baseh[k] = bh; bh += cnth[k]; }
  }
}

__global__ __launch_bounds__(256) void k_fill(const int* __restrict__ cls, const int* __restrict__ hrd,
    const int* __restrict__ bov, const int* __restrict__ boh,
    const int* __restrict__ basev, const int* __restrict__ baseh,
    int* __restrict__ posv, int* __restrict__ posh) {
  __shared__ int lc[256], lh[256];
  int t = threadIdx.x;
  int p = blockIdx.x * 256 + t;
  int s = cls[p]; int h = hrd[p];
  lc[t] = s; lh[t] = h;
  __syncthreads();
  if (s >= 0) {
    int rv = 0, rh = 0;
    for (int k = 0; k < t; ++k) { if (lc[k] == s) { rv++; rh += lh[k]; } }
    posv[basev[s] + bov[s * 256 + blockIdx.x] + rv] = p;
    if (h) posh[baseh[s] + boh[s * 256 + blockIdx.x] + rh] = p;
  }
}

// ---------------- K3: per-class sums from packed fp8 (thread-owns-channel) ----------------
__global__ __launch_bounds__(256) void k_sums(const uint32_t* __restrict__ pair8,
    const int* __restrict__ cls, float* __restrict__ gA, float* __restrict__ gB) {
  __shared__ float lacc[S_][2][C_];   // 38 KB
  __shared__ int scls[1024];
  int t = threadIdx.x;
  for (int e = t; e < S_ * 2 * C_; e += 256) (&lacc[0][0][0])[e] = 0.f;
  int p0 = blockIdx.x * 1024;
  for (int e = t; e < 1024; e += 256) scls[e] = cls[p0 + e];
  __syncthreads();
  int half = t & 1, dwi = t >> 1;
  for (int pp = 0; pp < 1024; ++pp) {
    int s = scls[pp];
    if (s < 0) continue;
    uint32_t d = pair8[(size_t)(p0 + pp) * 128 + dwi];
    v2f e0 = cvt8<0>(d), e1 = cvt8<1>(d);
    float mv = half ? e1.x : e0.x;
    float sv = half ? e1.y : e0.y;
    float ia = fastrcp(sv);
    lacc[s][0][t] += ia;
    lacc[s][1][t] += ia * mv;
  }
  __syncthreads();
  for (int e = t; e < S_ * C_; e += 256) {
    int s = e >> 8, c = e & 255;
    atomicAdd(&gA[e], lacc[s][0][c]);
    atomicAdd(&gB[e], lacc[s][1][c]);
  }
}

// ---------------- K4: prototypes ----------------
__global__ __launch_bounds__(256) void k_proto(const float* __restrict__ gA, const float* __restrict__ gB,
    const float* __restrict__ mmu, const float* __restrict__ msg,
    float* __restrict__ pmu, float* __restrict__ psig, float* __restrict__ phat) {
  int s = blockIdx.x, c = threadIdx.x;
  int e = s * C_ + c;
  float A = gA[e], Bv = gB[e];
  float psb = 1.0f / A;
  float pmb = psb * Bv;
  float ms = msg[e], mm = mmu[e];
  float ps = 1.0f / (1.0f / psb + 1.0f / ms);
  float pm = ps * (mm / ms + pmb / psb);
  pmu[e] = pm; psig[e] = ps;
  __shared__ float red[4];
  float w = wred(pm * pm);
  int lane = c & 63, wv = c >> 6;
  if (lane == 0) red[wv] = w;
  __syncthreads();
  float tot = red[0] + red[1] + red[2] + red[3];
  float nrm = fmaxf(sqrtf(tot), 1e-12f);
  phat[e] = pm / nrm;
}

// ---------------- K5a: sim -> log_softmax ----------------
__global__ __launch_bounds__(64) void k_simlogp(const float* __restrict__ phat,
    const float* __restrict__ psig, float* __restrict__ logp) {
  int i = blockIdx.x, lane = threadIdx.x;
  int c0 = lane * 4;
  float phi[4], psi[4];
#pragma unroll
  for (int k = 0; k < 4; ++k) { phi[k] = phat[i * C_ + c0 + k]; psi[k] = psig[i * C_ + c0 + k]; }
  float xs[18];
#pragma unroll
  for (int j = 0; j < 18; ++j) {
    int o = i + 1 + j; if (o >= S_) o -= S_;
    float t = 0.f;
#pragma unroll
    for (int k = 0; k < 4; ++k) {
      float d = phi[k] - phat[o * C_ + c0 + k];
      float dn = psi[k] + psig[o * C_ + c0 + k];
      t += d * d / dn + logf(dn);
    }
    t = wred(t);
    xs[j] = (-0.5f * t * (1.0f / 256.0f)) * 2.0f;
  }
  float m = xs[0];
#pragma unroll
  for (int j = 1; j < 18; ++j) m = fmaxf(m, xs[j]);
  float se = 0.f;
#pragma unroll
  for (int j = 0; j < 18; ++j) se += expf(xs[j] - m);
  float lg = logf(se);
  if (lane == 0) {
#pragma unroll
    for (int j = 0; j < 18; ++j) logp[i * 18 + j] = xs[j] - m - lg;
  }
}

// ---------------- K5d: anchors ----------------
__global__ __launch_bounds__(256) void k_anchors(const uint32_t* __restrict__ keys,
    const int* __restrict__ cnth, const int* __restrict__ baseh,
    const int* __restrict__ posh, int* __restrict__ aidx) {
  int i = blockIdx.x, q = threadIdx.x;
  uint32_t k0 = keys[i * 8 + 0], k1 = keys[i * 8 + 1];
  float u = bits2f01(rbits(k0, k1, (uint32_t)q));
  int cnt = cnth[i];
  int idx = P_ - 1;
  if (cnt > 0) {
    int kk = (int)(u * (float)cnt);
    if (kk >= cnt) kk = cnt - 1;
    idx = posh[baseh[i] + kk];
  }
  aidx[i * Q_ + q] = idx;
}

// ---------------- K5c: generalized prototypes ----------------
__global__ __launch_bounds__(256) void k_gen(const uint32_t* __restrict__ keys,
    const float* __restrict__ pmu, const float* __restrict__ psig, float* __restrict__ ghat) {
  int v = blockIdx.x, i = blockIdx.y, c = threadIdx.x;
  int o = i + 1 + (v >> 3); if (o >= S_) o -= S_;
  uint32_t k0 = keys[i * 8 + 6], k1 = keys[i * 8 + 7];
  uint32_t bits = rbits(k0, k1, (uint32_t)(v * C_ + c));
  float f01 = bits2f01(bits);
  const float lo = -0.99999994f;
  float u = fmaxf(f01 * 2.0f + lo, lo);
  float eps = 1.41421356237f * erfinv_f(u);
  float g = pmu[o * C_ + c] + sqrtf(psig[o * C_ + c]) * eps;
  __shared__ float red[4];
  float w = wred(g * g);
  int lane = c & 63, wv = c >> 6;
  if (lane == 0) red[wv] = w;
  __syncthreads();
  float tot = red[0] + red[1] + red[2] + red[3];
  float nrm = fmaxf(sqrtf(tot), 1e-12f);
  ghat[((size_t)(i * GENV_ + v)) * C_ + c] = g / nrm;
}

// ---------------- K5b: class + negative sampling ----------------
__global__ __launch_bounds__(256) void k_sample(const uint32_t* __restrict__ keys,
    const float* __restrict__ logp, const int* __restrict__ cntv, const int* __restrict__ basev,
    const int* __restrict__ posv, int* __restrict__ nidx) {
  int i = blockIdx.y;
  int m = blockIdx.x * 256 + threadIdx.x;
  __shared__ float lp[18];
  __shared__ int lcnt[S_], lbase[S_];
  int t = threadIdx.x;
  if (t < 18) lp[t] = logp[i * 18 + t];
  if (t < S_) { lcnt[t] = cntv[t]; lbase[t] = basev[t]; }
  __syncthreads();
  uint32_t kc0 = keys[i * 8 + 2], kc1 = keys[i * 8 + 3];
  uint32_t kn0 = keys[i * 8 + 4], kn1 = keys[i * 8 + 5];
  float bv = -1e30f; int best = 0;
  for (int s = 0; s < 18; ++s) {
    uint32_t b = rbits(kc0, kc1, (uint32_t)m * 18u + (uint32_t)s);
    float u = fmaxf(bits2f01(b), 1.17549435e-38f);
    float g = -__logf(-__logf(u)) + lp[s];
    if (g > bv) { bv = g; best = s; }
  }
  float un = bits2f01(rbits(kn0, kn1, (uint32_t)m));
  int cc = i + 1 + best; if (cc >= S_) cc -= S_;
  int cnt = lcnt[cc];
  int idx = P_ - 1;
  if (cnt > 0) {
    int kk = (int)(un * (float)cnt);
    if (kk >= cnt) kk = cnt - 1;
    idx = posv[lbase[cc] + kk];
  }
  nidx[(size_t)i * NS_ + m] = idx;
}

// ---------------- K6: main — block per anchor; lane-per-negative, fp8 rows ----------------
__global__ __launch_bounds__(256, 4) void k_main(const uint32_t* __restrict__ pair8,
    const float* __restrict__ norm2,
    const float* __restrict__ phat, const float* __restrict__ psig,
    const float* __restrict__ ghat, const int* __restrict__ aidx,
    const int* __restrict__ nidx, float* __restrict__ out) {
  __shared__ float2 ancA[C_];   // {ahat, asg}
  __shared__ float2 ancG[C_];   // {w, ahat*w}
  __shared__ float redm[3][4];
  __shared__ float2 mlw[4];

  int bid = blockIdx.x;
  int i = bid >> 8, q = bid & 255;
  int t = threadIdx.x, w = t >> 6, lane = t & 63;

  // ---- prep: anchor channel t ----
  int ap = aidx[bid];
  uint32_t ad = pair8[(size_t)ap * 128 + (t >> 1)];
  v2f ae0 = cvt8<0>(ad), ae1 = cvt8<1>(ad);
  float amu = (t & 1) ? ae1.x : ae0.x;
  float asg = (t & 1) ? ae1.y : ae0.y;
  float rn = fastrcp(fmaxf(sqrtf(norm2[ap]), 1e-12f));
  float ahat = amu * rn;
  float wv = fastrcp(asg);
  ancA[t] = make_float2(ahat, asg);
  ancG[t] = make_float2(wv, ahat * wv);

  float pm = phat[i * C_ + t];
  float ps = psig[i * C_ + t];
  float dnp = asg + ps;
  float dd = ahat - pm;
  float post = fmaf(dd * dd, fastrcp(dnp), __logf(dnp));
  float a1t = ahat * ahat * wv;
  float lat = __logf(asg);
  wred3(post, a1t, lat);
  if (lane == 0) { redm[0][w] = post; redm[1][w] = a1t; redm[2][w] = lat; }
  __syncthreads();
  float postS = redm[0][0] + redm[0][1] + redm[0][2] + redm[0][3];
  float Kc = (redm[1][0] + redm[1][1] + redm[1][2] + redm[1][3])
           + (redm[2][0] + redm[2][1] + redm[2][2] + redm[2][3]);
  float logit0 = -postS * (1.0f / 256.0f);

  // ---- negatives: lane owns rows j1, j1+64; 16 ch per iteration ----
  const int* nrow = nidx + (size_t)i * NS_ + (size_t)q * NEG_;
  int j1 = w * 128 + lane;
  int iA = nrow[j1], iB = nrow[j1 + 64];
  const uint4* rA = (const uint4*)(pair8 + (size_t)iA * 128);
  const uint4* rB = (const uint4*)(pair8 + (size_t)iB * 128);
  float rnA = fastrcp(fmaxf(sqrtf(norm2[iA]), 1e-12f));
  float rnB = fastrcp(fmaxf(sqrtf(norm2[iB]), 1e-12f));
  const float4* ancAf = (const float4*)ancA;
  const float4* ancGf = (const float4*)ancG;

  float sA1 = 0.f, sC1 = 0.f, sNR1 = 0.f, sL1 = 0.f;
  float sA2 = 0.f, sC2 = 0.f, sNR2 = 0.f, sL2 = 0.f;
  uint4 cA0 = rA[0], cA1 = rA[1], cB0 = rB[0], cB1 = rB[1];

  for (int it = 0; it < 16; ++it) {
    int nx = ((it + 1) & 15) << 1;
    uint4 pA0 = rA[nx], pA1 = rA[nx + 1], pB0 = rB[nx], pB1 = rB[nx + 1];
    float4 an[8];
#pragma unroll
    for (int r = 0; r < 8; ++r) an[r] = ancAf[it * 8 + r];
    uint32_t da[8] = {cA0.x, cA0.y, cA0.z, cA0.w, cA1.x, cA1.y, cA1.z, cA1.w};
    uint32_t db[8] = {cB0.x, cB0.y, cB0.z, cB0.w, cB1.x, cB1.y, cB1.z, cB1.w};
    float prA = 1.0f, prB = 1.0f;
#pragma unroll
    for (int j = 0; j < 8; ++j) {
      v2f a01 = cvt8<0>(da[j]), a23 = cvt8<1>(da[j]);
      v2f b01 = cvt8<0>(db[j]), b23 = cvt8<1>(db[j]);
      float4 ac = an[j];
      {
        float ah = ac.x, as_ = ac.y, ah2 = ah * ah;
        float dnA = as_ + a01.y; float rA_ = fastrcp(dnA); prA *= dnA;
        sA1 = fmaf(ah2, rA_, sA1); float qA = a01.x * rA_;
        sC1 = fmaf(ah, qA, sC1); sNR1 = fmaf(a01.x, qA, sNR1);
        float dnB = as_ + b01.y; float rB_ = fastrcp(dnB); prB *= dnB;
        sA2 = fmaf(ah2, rB_, sA2); float qB = b01.x * rB_;
        sC2 = fmaf(ah, qB, sC2); sNR2 = fmaf(b01.x, qB, sNR2);
      }
      {
        float ah = ac.z, as_ = ac.w, ah2 = ah * ah;
        float dnA = as_ + a23.y; float rA_ = fastrcp(dnA); prA *= dnA;
        sA1 = fmaf(ah2, rA_, sA1); float qA = a23.x * rA_;
        sC1 = fmaf(ah, qA, sC1); sNR1 = fmaf(a23.x, qA, sNR1);
        float dnB = as_ + b23.y; float rB_ = fastrcp(dnB); prB *= dnB;
        sA2 = fmaf(ah2, rB_, sA2); float qB = b23.x * rB_;
        sC2 = fmaf(ah, qB, sC2); sNR2 = fmaf(b23.x, qB, sNR2);
      }
    }
    sL1 += __logf(prA); sL2 += __logf(prB);
    cA0 = pA0; cA1 = pA1; cB0 = pB0; cB1 = pB1;
  }

  float m = -1e30f, l = 0.0f;
  {
    float tt1 = sA1 + rnA * rnA * sNR1 - 2.0f * rnA * sC1 + sL1;
    lse_up(-tt1 * (1.0f / 256.0f), m, l);
    float tt2 = sA2 + rnB * rnB * sNR2 - 2.0f * rnB * sC2 + sL2;
    lse_up(-tt2 * (1.0f / 256.0f), m, l);
  }

  // ---- gens: 36 per wave, lanes 0..35 ----
  if (lane < 36) {
    int g = lane * 4 + w;
    const float4* gp = (const float4*)(ghat + ((size_t)(i * GENV_ + g)) * C_);
    float a1 = 0.f, a2 = 0.f;
    for (int it = 0; it < 64; ++it) {
      float4 gv = gp[it];
      float4 g01 = ancGf[it * 2];
      float4 g23 = ancGf[it * 2 + 1];
      a1 = fmaf(gv.x * gv.x, g01.x, a1); a2 = fmaf(gv.x, g01.y, a2);
      a1 = fmaf(gv.y * gv.y, g01.z, a1); a2 = fmaf(gv.y, g01.w, a2);
      a1 = fmaf(gv.z * gv.z, g23.x, a1); a2 = fmaf(gv.z, g23.y, a2);
      a1 = fmaf(gv.w * gv.w, g23.z, a1); a2 = fmaf(gv.w, g23.w, a2);
    }
    float lg = -(Kc + a1 - 2.0f * a2) * (1.0f / 256.0f);
    lse_up(lg, m, l);
  }

  // ---- merge LSE ----
#pragma unroll
  for (int off = 32; off > 0; off >>= 1) {
    float mo = __shfl_xor(m, off, 64);
    float lo = __shfl_xor(l, off, 64);
    lse_merge(m, l, mo, lo);
  }
  if (lane == 0) mlw[w] = make_float2(m, l);
  __syncthreads();
  if (t == 0) {
    float mm = mlw[0].x, ll = mlw[0].y;
    lse_merge(mm, ll, mlw[1].x, mlw[1].y);
    lse_merge(mm, ll, mlw[2].x, mlw[2].y);
    lse_merge(mm, ll, mlw[3].x, mlw[3].y);
    lse_merge(mm, ll, logit0, 1.0f);
    float lse = mm + __logf(ll);
    float contrib = logit0 - lse;
    atomicAdd(out, -contrib * (1.0f / (19.0f * 256.0f)));
  }
}

// ---------------- host ----------------
extern "C" void kernel_launch(void* const* d_in, const int* in_sizes, int n_in,
                              void* d_out, int out_size, void* d_ws, size_t ws_size,
                              hipStream_t stream) {
  const float* mu    = (const float*)d_in[0];
  const float* sg    = (const float*)d_in[1];
  const float* label = (const float*)d_in[2];
  const float* mask  = (const float*)d_in[3];
  const float* prob  = (const float*)d_in[4];
  const float* mmu   = (const float*)d_in[5];
  const float* msg   = (const float*)d_in[6];

  char* ws = (char*)d_ws;
  size_t off = 0;
  auto take = [&](size_t bytes) { size_t r = off; off = (off + bytes + 255) & ~(size_t)255; return r; };
  size_t o_pair8 = take((size_t)P_ * 128 * 4);   // 32 MB
  size_t o_norm2 = take((size_t)P_ * 4);
  size_t o_cls   = take((size_t)P_ * 4);
  size_t o_hrd   = take((size_t)P_ * 4);
  size_t o_bcv   = take(S_ * 256 * 4);
  size_t o_bch   = take(S_ * 256 * 4);
  size_t o_bov   = take(S_ * 256 * 4);
  size_t o_boh   = take(S_ * 256 * 4);
  size_t o_cntv  = take(S_ * 4);
  size_t o_cnth  = take(S_ * 4);
  size_t o_basev = take(S_ * 4);
  size_t o_baseh = take(S_ * 4);
  size_t o_posv  = take((size_t)P_ * 4);
  size_t o_posh  = take((size_t)P_ * 4);
  size_t o_gAB   = take((size_t)2 * S_ * C_ * 4);
  size_t o_pmu   = take(S_ * C_ * 4);
  size_t o_psig  = take(S_ * C_ * 4);
  size_t o_phat  = take(S_ * C_ * 4);
  size_t o_logp  = take(S_ * 18 * 4);
  size_t o_keys  = take(S_ * 8 * 4);
  size_t o_aidx  = take(S_ * Q_ * 4);
  size_t o_nidx  = take((size_t)S_ * NS_ * 4);
  size_t o_ghat  = take((size_t)S_ * GENV_ * C_ * 4);
  if (ws_size < off) return;

  uint32_t* pair8 = (uint32_t*)(ws + o_pair8);
  float*    norm2 = (float*)(ws + o_norm2);
  int*      cls   = (int*)(ws + o_cls);
  int*      hrd   = (int*)(ws + o_hrd);
  int*      bcv   = (int*)(ws + o_bcv);
  int*      bch   = (int*)(ws + o_bch);
  int*      bov   = (int*)(ws + o_bov);
  int*      boh   = (int*)(ws + o_boh);
  int*      cntv  = (int*)(ws + o_cntv);
  int*      cnth  = (int*)(ws + o_cnth);
  int*      basev = (int*)(ws + o_basev);
  int*      baseh = (int*)(ws + o_baseh);
  int*      posv  = (int*)(ws + o_posv);
  int*      posh  = (int*)(ws + o_posh);
  float*    gA    = (float*)(ws + o_gAB);
  float*    gB    = gA + S_ * C_;
  float*    pmu   = (float*)(ws + o_pmu);
  float*    psig  = (float*)(ws + o_psig);
  float*    phat  = (float*)(ws + o_phat);
  float*    logp  = (float*)(ws + o_logp);
  uint32_t* keys  = (uint32_t*)(ws + o_keys);
  int*      aidx  = (int*)(ws + o_aidx);
  int*      nidx  = (int*)(ws + o_nidx);
  float*    ghat  = (float*)(ws + o_ghat);

  hipMemsetAsync(ws + o_gAB, 0, (size_t)2 * S_ * C_ * 4, stream);
  hipMemsetAsync(ws + o_norm2, 0, (size_t)P_ * 4, stream);
  hipMemsetAsync(d_out, 0, (size_t)out_size * 4, stream);

  k_keys<<<1, 64, 0, stream>>>(keys);
  k_classify<<<256, 256, 0, stream>>>(label, mask, prob, cls, hrd);
  k_pack<<<dim3(P_ / 64, C_ / 64), 256, 0, stream>>>(mu, sg, pair8, norm2);
  k_count<<<256, 256, 0, stream>>>(cls, hrd, bcv, bch);
  k_scan<<<1, 64, 0, stream>>>(bcv, bch, bov, boh, cntv, cnth, basev, baseh);
  k_fill<<<256, 256, 0, stream>>>(cls, hrd, bov, boh, basev, baseh, posv, posh);
  k_sums<<<64, 256, 0, stream>>>(pair8, cls, gA, gB);
  k_proto<<<S_, 256, 0, stream>>>(gA, gB, mmu, msg, pmu, psig, phat);
  k_simlogp<<<S_, 64, 0, stream>>>(phat, psig, logp);
  k_anchors<<<S_, 256, 0, stream>>>(keys, cnth, baseh, posh, aidx);
  k_gen<<<dim3(GENV_, S_), 256, 0, stream>>>(keys, pmu, psig, ghat);
  k_sample<<<dim3(512, S_), 256, 0, stream>>>(keys, logp, cntv, basev, posv, nidx);
  k_main<<<S_ * Q_, 256, 0, stream>>>(pair8, norm2, phat, psig, ghat, aidx, nidx, (float*)d_out);
}

// Round 4
// 796.233 us; speedup vs baseline: 1.7619x; 1.1615x over previous
//
#include <hip/hip_runtime.h>
#include <hip/hip_fp16.h>
#include <hip/hip_fp8.h>
#include <cstdint>

#define B_   4
#define S_   19
#define HW_  16384
#define P_   65536
#define C_   256
#define Q_   256
#define NEG_ 512
#define NS_  131072
#define GENV_ 144

typedef float v2f __attribute__((ext_vector_type(2)));

#if __has_builtin(__builtin_amdgcn_cvt_pk_f32_fp8) && __has_builtin(__builtin_amdgcn_cvt_pk_fp8_f32)
#define HAVE_HW_FP8 1
#endif

template<int W> __device__ __forceinline__ v2f cvt8(uint32_t d) {
#ifdef HAVE_HW_FP8
  v2f r = __builtin_amdgcn_cvt_pk_f32_fp8((int)d, W);
  return r;
#else
  __hip_fp8_e4m3 h0, h1;
  h0.__x = (uint8_t)(d >> (W * 16));
  h1.__x = (uint8_t)(d >> (W * 16 + 8));
  v2f r; r.x = (float)h0; r.y = (float)h1; return r;
#endif
}
template<int W> __device__ __forceinline__ uint32_t pk8(float a, float b, uint32_t old) {
#ifdef HAVE_HW_FP8
  return (uint32_t)__builtin_amdgcn_cvt_pk_fp8_f32(a, b, (int)old, W);
#else
  __hip_fp8_e4m3 ha(a), hb(b);
  uint32_t v = (uint32_t)ha.__x | ((uint32_t)hb.__x << 8);
  return (old & (W ? 0x0000FFFFu : 0xFFFF0000u)) | (v << (W * 16));
#endif
}

// ---------------- threefry2x32 (JAX-exact) ----------------
__device__ __forceinline__ void tf2x32(uint32_t k0, uint32_t k1, uint32_t x0, uint32_t x1,
                                       uint32_t& o0, uint32_t& o1) {
  uint32_t k2 = k0 ^ k1 ^ 0x1BD11BDAu;
#define TFR(r) { x0 += x1; x1 = (x1 << r) | (x1 >> (32 - r)); x1 ^= x0; }
  x0 += k0; x1 += k1;
  TFR(13) TFR(15) TFR(26) TFR(6)  x0 += k1; x1 += k2 + 1u;
  TFR(17) TFR(29) TFR(16) TFR(24) x0 += k2; x1 += k0 + 2u;
  TFR(13) TFR(15) TFR(26) TFR(6)  x0 += k0; x1 += k1 + 3u;
  TFR(17) TFR(29) TFR(16) TFR(24) x0 += k1; x1 += k2 + 4u;
  TFR(13) TFR(15) TFR(26) TFR(6)  x0 += k2; x1 += k0 + 5u;
#undef TFR
  o0 = x0; o1 = x1;
}

__device__ __forceinline__ uint32_t rbits(uint32_t k0, uint32_t k1, uint32_t n) {
  uint32_t a, b; tf2x32(k0, k1, 0u, n, a, b); return a ^ b;
}

__device__ __forceinline__ float bits2f01(uint32_t b) {
  return __uint_as_float((b >> 9) | 0x3f800000u) - 1.0f;
}

__device__ __forceinline__ float fastrcp(float x) {
  float r; asm("v_rcp_f32 %0, %1" : "=v"(r) : "v"(x)); return r;
}

__device__ __forceinline__ float wred(float v) {
#pragma unroll
  for (int off = 32; off > 0; off >>= 1) v += __shfl_xor(v, off, 64);
  return v;
}
__device__ __forceinline__ void wred3(float& a, float& b, float& c) {
#pragma unroll
  for (int off = 32; off > 0; off >>= 1) {
    a += __shfl_xor(a, off, 64);
    b += __shfl_xor(b, off, 64);
    c += __shfl_xor(c, off, 64);
  }
}

__device__ __forceinline__ void lse_up(float lg, float& m, float& l) {
  if (lg > m) { l = l * __expf(m - lg) + 1.0f; m = lg; }
  else l += __expf(lg - m);
}
__device__ __forceinline__ void lse_merge(float& m, float& l, float mo, float lo) {
  float mn = fmaxf(m, mo);
  l = l * __expf(m - mn) + lo * __expf(mo - mn);
  m = mn;
}

// XLA ErfInv32 (Giles)
__device__ __forceinline__ float erfinv_f(float x) {
  float w = -__logf(fmaxf(fmaf(-x, x, 1.0f), 1e-37f));
  float p;
  if (w < 5.0f) {
    w -= 2.5f;
    p = 2.81022636e-08f;
    p = fmaf(p, w, 3.43273939e-07f);
    p = fmaf(p, w, -3.5233877e-06f);
    p = fmaf(p, w, -4.39150654e-06f);
    p = fmaf(p, w, 0.00021858087f);
    p = fmaf(p, w, -0.00125372503f);
    p = fmaf(p, w, -0.00417768164f);
    p = fmaf(p, w, 0.246640727f);
    p = fmaf(p, w, 1.50140941f);
  } else {
    w = sqrtf(w) - 3.0f;
    p = -0.000200214257f;
    p = fmaf(p, w, 0.000100950558f);
    p = fmaf(p, w, 0.00134934322f);
    p = fmaf(p, w, -0.00367342844f);
    p = fmaf(p, w, 0.00573950773f);
    p = fmaf(p, w, -0.0076224613f);
    p = fmaf(p, w, 0.00943887047f);
    p = fmaf(p, w, 1.00167406f);
    p = fmaf(p, w, 2.83297682f);
  }
  return p * x;
}

// ---------------- K0: per-class keys ----------------
__global__ void k_keys(uint32_t* __restrict__ keys) {
  int i = threadIdx.x;
  if (i >= S_) return;
  uint32_t f0, f1;
  tf2x32(0u, 1234u, 0u, (uint32_t)i, f0, f1);
#pragma unroll
  for (int t = 0; t < 4; ++t) {
    uint32_t a, b;
    tf2x32(f0, f1, 0u, (uint32_t)t, a, b);
    keys[i * 8 + t * 2] = a; keys[i * 8 + t * 2 + 1] = b;
  }
}

// ---------------- K1: class id + hard flag ----------------
__global__ __launch_bounds__(256) void k_classify(const float* __restrict__ label,
    const float* __restrict__ mask, const float* __restrict__ prob,
    int* __restrict__ cls, int* __restrict__ hrd) {
  int p = blockIdx.x * 256 + threadIdx.x;
  int b = p >> 14, rem = p & (HW_ - 1);
  int sp = -1;
#pragma unroll
  for (int s = 0; s < S_; ++s) {
    float l = label[((b * S_ + s) << 14) + rem];
    if (l > 0.5f) sp = s;
  }
  if (mask[(b << 14) + rem] <= 0.5f) sp = -1;
  int h = 0;
  if (sp >= 0) h = (prob[((b * S_ + sp) << 14) + rem] < 0.97f) ? 1 : 0;
  cls[p] = sp; hrd[p] = h;
}

// ---------------- K1b: pack (B,C,H,W) f32 -> (P,C) fp8 pair + norm2 ----------------
__global__ __launch_bounds__(256) void k_pack(const float* __restrict__ mu,
    const float* __restrict__ sg, uint32_t* __restrict__ pair8, float* __restrict__ norm2) {
  __shared__ float smu[64][65];
  __shared__ float ssg[64][65];
  int p0 = blockIdx.x * 64, c0 = blockIdx.y * 64;
  int b = p0 >> 14, rem0 = p0 & (HW_ - 1);
  int px = threadIdx.x & 63, cy = threadIdx.x >> 6;
#pragma unroll
  for (int itr = 0; itr < 16; ++itr) {
    int cl = cy + itr * 4;
    int addr = ((b * C_ + c0 + cl) << 14) + rem0 + px;
    smu[cl][px] = mu[addr];
    ssg[cl][px] = sg[addr];
  }
  __syncthreads();
#pragma unroll
  for (int itr = 0; itr < 8; ++itr) {
    int e = itr * 256 + threadIdx.x;
    int pxl = e >> 5, dw = e & 31, cl = dw * 2;
    uint32_t wd = pk8<0>(smu[cl][pxl], ssg[cl][pxl], 0u);
    wd = pk8<1>(smu[cl + 1][pxl], ssg[cl + 1][pxl], wd);
    pair8[(size_t)(p0 + pxl) * 128 + (c0 >> 1) + dw] = wd;
  }
  int pxn = threadIdx.x >> 2, qn = threadIdx.x & 3;
  float s2 = 0.f;
#pragma unroll
  for (int k = 0; k < 16; ++k) { float v = smu[qn * 16 + k][pxn]; s2 = fmaf(v, v, s2); }
  s2 += __shfl_xor(s2, 1, 64);
  s2 += __shfl_xor(s2, 2, 64);
  if (qn == 0) atomicAdd(&norm2[p0 + pxn], s2);
}

// ---------------- K2: ordered per-class pixel lists ----------------
__global__ __launch_bounds__(256) void k_count(const int* __restrict__ cls, const int* __restrict__ hrd,
    int* __restrict__ bcv, int* __restrict__ bch) {
  __shared__ int hv[S_], hh[S_];
  int t = threadIdx.x;
  if (t < S_) { hv[t] = 0; hh[t] = 0; }
  __syncthreads();
  int p = blockIdx.x * 256 + t;
  int s = cls[p];
  if (s >= 0) { atomicAdd(&hv[s], 1); if (hrd[p]) atomicAdd(&hh[s], 1); }
  __syncthreads();
  if (t < S_) { bcv[t * 256 + blockIdx.x] = hv[t]; bch[t * 256 + blockIdx.x] = hh[t]; }
}

// parallel two-level scan: 304 workers of 16-entry chunks
__global__ __launch_bounds__(320) void k_scan(const int* __restrict__ bcv, const int* __restrict__ bch,
    int* __restrict__ bov, int* __restrict__ boh,
    int* __restrict__ cntv, int* __restrict__ cnth,
    int* __restrict__ basev, int* __restrict__ baseh) {
  __shared__ int psv[S_][16], psh[S_][16], scv[S_], sch[S_];
  int t = threadIdx.x;
  int s = t >> 4, c = t & 15;
  if (t < 304) {
    int sv = 0, sh = 0;
#pragma unroll 4
    for (int b = 0; b < 16; ++b) {
      sv += bcv[s * 256 + c * 16 + b];
      sh += bch[s * 256 + c * 16 + b];
    }
    psv[s][c] = sv; psh[s][c] = sh;
  }
  __syncthreads();
  if (t < S_) {
    int rv = 0, rh = 0;
#pragma unroll
    for (int cc = 0; cc < 16; ++cc) {
      int tv = psv[t][cc]; psv[t][cc] = rv; rv += tv;
      int th = psh[t][cc]; psh[t][cc] = rh; rh += th;
    }
    cntv[t] = rv; cnth[t] = rh; scv[t] = rv; sch[t] = rh;
  }
  __syncthreads();
  if (t == 0) {
    int bv = 0, bh = 0;
    for (int k = 0; k < S_; ++k) { basev[k] = bv; bv += scv[k]; baseh[k] = bh; bh += sch[k]; }
  }
  if (t < 304) {
    int rv = psv[s][c], rh = psh[s][c];
#pragma unroll 4
    for (int b = 0; b < 16; ++b) {
      int i0 = s * 256 + c * 16 + b;
      int tv = bcv[i0]; bov[i0] = rv; rv += tv;
      int th = bch[i0]; boh[i0] = rh; rh += th;
    }
  }
}

__global__ __launch_bounds__(256) void k_fill(const int* __restrict__ cls, const int* __restrict__ hrd,
    const int* __restrict__ bov, const int* __restrict__ boh,
    const int* __restrict__ basev, const int* __restrict__ baseh,
    int* __restrict__ posv, int* __restrict__ posh) {
  __shared__ int lc[256], lh[256];
  int t = threadIdx.x;
  int p = blockIdx.x * 256 + t;
  int s = cls[p]; int h = hrd[p];
  lc[t] = s; lh[t] = h;
  __syncthreads();
  if (s >= 0) {
    int rv = 0, rh = 0;
    for (int k = 0; k < t; ++k) { if (lc[k] == s) { rv++; rh += lh[k]; } }
    posv[basev[s] + bov[s * 256 + blockIdx.x] + rv] = p;
    if (h) posh[baseh[s] + boh[s * 256 + blockIdx.x] + rh] = p;
  }
}

// ---------------- K3: per-class partial sums (no global atomics) ----------------
__global__ __launch_bounds__(256) void k_sums(const uint32_t* __restrict__ pair8,
    const int* __restrict__ cls, float* __restrict__ part) {
  __shared__ float lacc[S_][2][C_];   // 38 KB
  __shared__ int scls[256];
  int t = threadIdx.x;
  for (int e = t; e < S_ * 2 * C_; e += 256) (&lacc[0][0][0])[e] = 0.f;
  int p0 = blockIdx.x * 256;
  scls[t] = cls[p0 + t];
  __syncthreads();
  int half = t & 1, dwi = t >> 1;
  uint32_t d = pair8[(size_t)p0 * 128 + dwi];
  for (int pp = 0; pp < 256; ++pp) {
    uint32_t dnx = (pp + 1 < 256) ? pair8[(size_t)(p0 + pp + 1) * 128 + dwi] : 0u;
    int s = scls[pp];
    if (s >= 0) {
      v2f e = half ? cvt8<1>(d) : cvt8<0>(d);
      float ia = fastrcp(e.y);
      lacc[s][0][t] += ia;
      lacc[s][1][t] += ia * e.x;
    }
    d = dnx;
  }
  __syncthreads();
  float* dst = part + (size_t)blockIdx.x * (2 * S_ * C_);
  for (int e = t; e < S_ * 2 * C_; e += 256) dst[e] = (&lacc[0][0][0])[e];
}

// ---------------- K4: prototypes (reduce partials here) ----------------
__global__ __launch_bounds__(256) void k_proto(const float* __restrict__ part,
    const float* __restrict__ mmu, const float* __restrict__ msg,
    float* __restrict__ pmu, float* __restrict__ psig, float* __restrict__ phat) {
  int s = blockIdx.x, c = threadIdx.x;
  float A = 0.f, Bv = 0.f;
  for (int b = 0; b < 256; ++b) {
    const float* pb = part + (size_t)b * (2 * S_ * C_) + (s * 2) * C_;
    A += pb[c];
    Bv += pb[C_ + c];
  }
  int e = s * C_ + c;
  float psb = 1.0f / A;
  float pmb = psb * Bv;
  float ms = msg[e], mm = mmu[e];
  float ps = 1.0f / (1.0f / psb + 1.0f / ms);
  float pm = ps * (mm / ms + pmb / psb);
  pmu[e] = pm; psig[e] = ps;
  __shared__ float red[4];
  float w = wred(pm * pm);
  int lane = c & 63, wv = c >> 6;
  if (lane == 0) red[wv] = w;
  __syncthreads();
  float tot = red[0] + red[1] + red[2] + red[3];
  float nrm = fmaxf(sqrtf(tot), 1e-12f);
  phat[e] = pm / nrm;
}

// ---------------- K5a: sim -> log_softmax ----------------
__global__ __launch_bounds__(64) void k_simlogp(const float* __restrict__ phat,
    const float* __restrict__ psig, float* __restrict__ logp) {
  int i = blockIdx.x, lane = threadIdx.x;
  int c0 = lane * 4;
  float phi[4], psi[4];
#pragma unroll
  for (int k = 0; k < 4; ++k) { phi[k] = phat[i * C_ + c0 + k]; psi[k] = psig[i * C_ + c0 + k]; }
  float xs[18];
#pragma unroll
  for (int j = 0; j < 18; ++j) {
    int o = i + 1 + j; if (o >= S_) o -= S_;
    float t = 0.f;
#pragma unroll
    for (int k = 0; k < 4; ++k) {
      float d = phi[k] - phat[o * C_ + c0 + k];
      float dn = psi[k] + psig[o * C_ + c0 + k];
      t += d * d / dn + logf(dn);
    }
    t = wred(t);
    xs[j] = (-0.5f * t * (1.0f / 256.0f)) * 2.0f;
  }
  float m = xs[0];
#pragma unroll
  for (int j = 1; j < 18; ++j) m = fmaxf(m, xs[j]);
  float se = 0.f;
#pragma unroll
  for (int j = 0; j < 18; ++j) se += expf(xs[j] - m);
  float lg = logf(se);
  if (lane == 0) {
#pragma unroll
    for (int j = 0; j < 18; ++j) logp[i * 18 + j] = xs[j] - m - lg;
  }
}

// ---------------- K5d: anchors ----------------
__global__ __launch_bounds__(256) void k_anchors(const uint32_t* __restrict__ keys,
    const int* __restrict__ cnth, const int* __restrict__ baseh,
    const int* __restrict__ posh, int* __restrict__ aidx) {
  int i = blockIdx.x, q = threadIdx.x;
  uint32_t k0 = keys[i * 8 + 0], k1 = keys[i * 8 + 1];
  float u = bits2f01(rbits(k0, k1, (uint32_t)q));
  int cnt = cnth[i];
  int idx = P_ - 1;
  if (cnt > 0) {
    int kk = (int)(u * (float)cnt);
    if (kk >= cnt) kk = cnt - 1;
    idx = posh[baseh[i] + kk];
  }
  aidx[i * Q_ + q] = idx;
}

// ---------------- K5c: generalized prototypes ----------------
__global__ __launch_bounds__(256) void k_gen(const uint32_t* __restrict__ keys,
    const float* __restrict__ pmu, const float* __restrict__ psig, float* __restrict__ ghat) {
  int v = blockIdx.x, i = blockIdx.y, c = threadIdx.x;
  int o = i + 1 + (v >> 3); if (o >= S_) o -= S_;
  uint32_t k0 = keys[i * 8 + 6], k1 = keys[i * 8 + 7];
  uint32_t bits = rbits(k0, k1, (uint32_t)(v * C_ + c));
  float f01 = bits2f01(bits);
  const float lo = -0.99999994f;
  float u = fmaxf(f01 * 2.0f + lo, lo);
  float eps = 1.41421356237f * erfinv_f(u);
  float g = pmu[o * C_ + c] + sqrtf(psig[o * C_ + c]) * eps;
  __shared__ float red[4];
  float w = wred(g * g);
  int lane = c & 63, wv = c >> 6;
  if (lane == 0) red[wv] = w;
  __syncthreads();
  float tot = red[0] + red[1] + red[2] + red[3];
  float nrm = fmaxf(sqrtf(tot), 1e-12f);
  ghat[((size_t)(i * GENV_ + v)) * C_ + c] = g / nrm;
}

// ---------------- K5b: class + negative sampling ----------------
__global__ __launch_bounds__(256) void k_sample(const uint32_t* __restrict__ keys,
    const float* __restrict__ logp, const int* __restrict__ cntv, const int* __restrict__ basev,
    const int* __restrict__ posv, int* __restrict__ nidx) {
  int i = blockIdx.y;
  int m = blockIdx.x * 256 + threadIdx.x;
  __shared__ float lp[18];
  __shared__ int lcnt[S_], lbase[S_];
  int t = threadIdx.x;
  if (t < 18) lp[t] = logp[i * 18 + t];
  if (t < S_) { lcnt[t] = cntv[t]; lbase[t] = basev[t]; }
  __syncthreads();
  uint32_t kc0 = keys[i * 8 + 2], kc1 = keys[i * 8 + 3];
  uint32_t kn0 = keys[i * 8 + 4], kn1 = keys[i * 8 + 5];
  float bv = -1e30f; int best = 0;
  for (int s = 0; s < 18; ++s) {
    uint32_t b = rbits(kc0, kc1, (uint32_t)m * 18u + (uint32_t)s);
    float u = fmaxf(bits2f01(b), 1.17549435e-38f);
    float g = -__logf(-__logf(u)) + lp[s];
    if (g > bv) { bv = g; best = s; }
  }
  float un = bits2f01(rbits(kn0, kn1, (uint32_t)m));
  int cc = i + 1 + best; if (cc >= S_) cc -= S_;
  int cnt = lcnt[cc];
  int idx = P_ - 1;
  if (cnt > 0) {
    int kk = (int)(un * (float)cnt);
    if (kk >= cnt) kk = cnt - 1;
    idx = posv[lbase[cc] + kk];
  }
  nidx[(size_t)i * NS_ + m] = idx;
}

// ---------------- K6: main ----------------
#define CH2(dwA, dwB, ACIDX) {                                    \
    float4 ac = ancAf[ACIDX];                                     \
    v2f aa0 = cvt8<0>(dwA), aa1 = cvt8<1>(dwA);                   \
    v2f bb0 = cvt8<0>(dwB), bb1 = cvt8<1>(dwB);                   \
    { float ah = ac.x, as_ = ac.y, ah2 = ah * ah;                 \
      float dnA = as_ + aa0.y; float rA_ = fastrcp(dnA); prA *= dnA; \
      sA1 = fmaf(ah2, rA_, sA1); float qA = aa0.x * rA_;          \
      sC1 = fmaf(ah, qA, sC1); sNR1 = fmaf(aa0.x, qA, sNR1);      \
      float dnB = as_ + bb0.y; float rB_ = fastrcp(dnB); prB *= dnB; \
      sA2 = fmaf(ah2, rB_, sA2); float qB = bb0.x * rB_;          \
      sC2 = fmaf(ah, qB, sC2); sNR2 = fmaf(bb0.x, qB, sNR2); }    \
    { float ah = ac.z, as_ = ac.w, ah2 = ah * ah;                 \
      float dnA = as_ + aa1.y; float rA_ = fastrcp(dnA); prA *= dnA; \
      sA1 = fmaf(ah2, rA_, sA1); float qA = aa1.x * rA_;          \
      sC1 = fmaf(ah, qA, sC1); sNR1 = fmaf(aa1.x, qA, sNR1);      \
      float dnB = as_ + bb1.y; float rB_ = fastrcp(dnB); prB *= dnB; \
      sA2 = fmaf(ah2, rB_, sA2); float qB = bb1.x * rB_;          \
      sC2 = fmaf(ah, qB, sC2); sNR2 = fmaf(bb1.x, qB, sNR2); } }

#define PROC16(c0v, c1v, d0v, d1v, base) {                        \
    CH2(c0v.x, d0v.x, (base) + 0) CH2(c0v.y, d0v.y, (base) + 1)   \
    CH2(c0v.z, d0v.z, (base) + 2) CH2(c0v.w, d0v.w, (base) + 3)   \
    CH2(c1v.x, d1v.x, (base) + 4) CH2(c1v.y, d1v.y, (base) + 5)   \
    CH2(c1v.z, d1v.z, (base) + 6) CH2(c1v.w, d1v.w, (base) + 7) }

__global__ __launch_bounds__(256, 4) void k_main(const uint32_t* __restrict__ pair8,
    const float* __restrict__ norm2,
    const float* __restrict__ phat, const float* __restrict__ psig,
    const float* __restrict__ ghat, const int* __restrict__ aidx,
    const int* __restrict__ nidx, float* __restrict__ out) {
  __shared__ float2 ancA[C_];   // {ahat, asg}
  __shared__ float2 ancG[C_];   // {w, ahat*w}
  __shared__ float redm[3][4];
  __shared__ float2 mlw[4];

  int bid = blockIdx.x;
  int i = bid >> 8, q = bid & 255;
  int t = threadIdx.x, w = t >> 6, lane = t & 63;

  // ---- prep: anchor channel t ----
  int ap = aidx[bid];
  uint32_t ad = pair8[(size_t)ap * 128 + (t >> 1)];
  v2f ae0 = cvt8<0>(ad), ae1 = cvt8<1>(ad);
  float amu = (t & 1) ? ae1.x : ae0.x;
  float asg = (t & 1) ? ae1.y : ae0.y;
  float rn = fastrcp(fmaxf(sqrtf(norm2[ap]), 1e-12f));
  float ahat = amu * rn;
  float wv = fastrcp(asg);
  ancA[t] = make_float2(ahat, asg);
  ancG[t] = make_float2(wv, ahat * wv);

  float pm = phat[i * C_ + t];
  float ps = psig[i * C_ + t];
  float dnp = asg + ps;
  float dd = ahat - pm;
  float post = fmaf(dd * dd, fastrcp(dnp), __logf(dnp));
  float a1t = ahat * ahat * wv;
  float lat = __logf(asg);
  wred3(post, a1t, lat);
  if (lane == 0) { redm[0][w] = post; redm[1][w] = a1t; redm[2][w] = lat; }
  __syncthreads();
  float postS = redm[0][0] + redm[0][1] + redm[0][2] + redm[0][3];
  float Kc = (redm[1][0] + redm[1][1] + redm[1][2] + redm[1][3])
           + (redm[2][0] + redm[2][1] + redm[2][2] + redm[2][3]);
  float logit0 = -postS * (1.0f / 256.0f);

  // ---- negatives: lane owns rows j1, j1+64; ping-pong 16-ch chunks ----
  const int* nrow = nidx + (size_t)i * NS_ + (size_t)q * NEG_;
  int j1 = w * 128 + lane;
  int iA = nrow[j1], iB = nrow[j1 + 64];
  const uint4* rA = (const uint4*)(pair8 + (size_t)iA * 128);
  const uint4* rB = (const uint4*)(pair8 + (size_t)iB * 128);
  float rnA = fastrcp(fmaxf(sqrtf(norm2[iA]), 1e-12f));
  float rnB = fastrcp(fmaxf(sqrtf(norm2[iB]), 1e-12f));
  const float4* ancAf = (const float4*)ancA;
  const float4* ancGf = (const float4*)ancG;

  float sA1 = 0.f, sC1 = 0.f, sNR1 = 0.f, sL1 = 0.f;
  float sA2 = 0.f, sC2 = 0.f, sNR2 = 0.f, sL2 = 0.f;

  uint4 A0 = rA[0], A1 = rA[1], B0 = rB[0], B1 = rB[1];
  uint4 A2, A3, B2, B3;

#pragma unroll 1
  for (int it = 0; it < 16; it += 2) {
    int nx = (it + 1) * 2;
    A2 = rA[nx]; A3 = rA[nx + 1]; B2 = rB[nx]; B3 = rB[nx + 1];
    float prA = 1.0f, prB = 1.0f;
    PROC16(A0, A1, B0, B1, it * 8);
    float prAs = prA, prBs = prB;
    int nx2 = ((it + 2) & 15) * 2;
    A0 = rA[nx2]; A1 = rA[nx2 + 1]; B0 = rB[nx2]; B1 = rB[nx2 + 1];
    prA = 1.0f; prB = 1.0f;
    PROC16(A2, A3, B2, B3, (it + 1) * 8);
    sL1 += __logf(prAs * prA);     // 32-channel product: range [0.2^32, 2^32] safe
    sL2 += __logf(prBs * prB);
  }

  float m = -1e30f, l = 0.0f;
  {
    float tt1 = sA1 + rnA * rnA * sNR1 - 2.0f * rnA * sC1 + sL1;
    lse_up(-tt1 * (1.0f / 256.0f), m, l);
    float tt2 = sA2 + rnB * rnB * sNR2 - 2.0f * rnB * sC2 + sL2;
    lse_up(-tt2 * (1.0f / 256.0f), m, l);
  }

  // ---- gens: 36 per wave, lanes 0..35 ----
  if (lane < 36) {
    int g = lane * 4 + w;
    const float4* gp = (const float4*)(ghat + ((size_t)(i * GENV_ + g)) * C_);
    float a1 = 0.f, a2 = 0.f;
    for (int itr = 0; itr < 64; ++itr) {
      float4 gv = gp[itr];
      float4 g01 = ancGf[itr * 2];
      float4 g23 = ancGf[itr * 2 + 1];
      a1 = fmaf(gv.x * gv.x, g01.x, a1); a2 = fmaf(gv.x, g01.y, a2);
      a1 = fmaf(gv.y * gv.y, g01.z, a1); a2 = fmaf(gv.y, g01.w, a2);
      a1 = fmaf(gv.z * gv.z, g23.x, a1); a2 = fmaf(gv.z, g23.y, a2);
      a1 = fmaf(gv.w * gv.w, g23.z, a1); a2 = fmaf(gv.w, g23.w, a2);
    }
    float lg = -(Kc + a1 - 2.0f * a2) * (1.0f / 256.0f);
    lse_up(lg, m, l);
  }

  // ---- merge LSE ----
#pragma unroll
  for (int off = 32; off > 0; off >>= 1) {
    float mo = __shfl_xor(m, off, 64);
    float lo = __shfl_xor(l, off, 64);
    lse_merge(m, l, mo, lo);
  }
  if (lane == 0) mlw[w] = make_float2(m, l);
  __syncthreads();
  if (t == 0) {
    float mm = mlw[0].x, ll = mlw[0].y;
    lse_merge(mm, ll, mlw[1].x, mlw[1].y);
    lse_merge(mm, ll, mlw[2].x, mlw[2].y);
    lse_merge(mm, ll, mlw[3].x, mlw[3].y);
    lse_merge(mm, ll, logit0, 1.0f);
    float lse = mm + __logf(ll);
    float contrib = logit0 - lse;
    atomicAdd(out, -contrib * (1.0f / (19.0f * 256.0f)));
  }
}

// ---------------- host ----------------
extern "C" void kernel_launch(void* const* d_in, const int* in_sizes, int n_in,
                              void* d_out, int out_size, void* d_ws, size_t ws_size,
                              hipStream_t stream) {
  const float* mu    = (const float*)d_in[0];
  const float* sg    = (const float*)d_in[1];
  const float* label = (const float*)d_in[2];
  const float* mask  = (const float*)d_in[3];
  const float* prob  = (const float*)d_in[4];
  const float* mmu   = (const float*)d_in[5];
  const float* msg   = (const float*)d_in[6];

  char* ws = (char*)d_ws;
  size_t off = 0;
  auto take = [&](size_t bytes) { size_t r = off; off = (off + bytes + 255) & ~(size_t)255; return r; };
  size_t o_pair8 = take((size_t)P_ * 128 * 4);   // 32 MB
  size_t o_norm2 = take((size_t)P_ * 4);
  size_t o_cls   = take((size_t)P_ * 4);
  size_t o_hrd   = take((size_t)P_ * 4);
  size_t o_bcv   = take(S_ * 256 * 4);
  size_t o_bch   = take(S_ * 256 * 4);
  size_t o_bov   = take(S_ * 256 * 4);
  size_t o_boh   = take(S_ * 256 * 4);
  size_t o_cntv  = take(S_ * 4);
  size_t o_cnth  = take(S_ * 4);
  size_t o_basev = take(S_ * 4);
  size_t o_baseh = take(S_ * 4);
  size_t o_posv  = take((size_t)P_ * 4);
  size_t o_posh  = take((size_t)P_ * 4);
  size_t o_part  = take((size_t)256 * 2 * S_ * C_ * 4);  // ~10 MB
  size_t o_pmu   = take(S_ * C_ * 4);
  size_t o_psig  = take(S_ * C_ * 4);
  size_t o_phat  = take(S_ * C_ * 4);
  size_t o_logp  = take(S_ * 18 * 4);
  size_t o_keys  = take(S_ * 8 * 4);
  size_t o_aidx  = take(S_ * Q_ * 4);
  size_t o_nidx  = take((size_t)S_ * NS_ * 4);
  size_t o_ghat  = take((size_t)S_ * GENV_ * C_ * 4);
  if (ws_size < off) return;

  uint32_t* pair8 = (uint32_t*)(ws + o_pair8);
  float*    norm2 = (float*)(ws + o_norm2);
  int*      cls   = (int*)(ws + o_cls);
  int*      hrd   = (int*)(ws + o_hrd);
  int*      bcv   = (int*)(ws + o_bcv);
  int*      bch   = (int*)(ws + o_bch);
  int*      bov   = (int*)(ws + o_bov);
  int*      boh   = (int*)(ws + o_boh);
  int*      cntv  = (int*)(ws + o_cntv);
  int*      cnth  = (int*)(ws + o_cnth);
  int*      basev = (int*)(ws + o_basev);
  int*      baseh = (int*)(ws + o_baseh);
  int*      posv  = (int*)(ws + o_posv);
  int*      posh  = (int*)(ws + o_posh);
  float*    part  = (float*)(ws + o_part);
  float*    pmu   = (float*)(ws + o_pmu);
  float*    psig  = (float*)(ws + o_psig);
  float*    phat  = (float*)(ws + o_phat);
  float*    logp  = (float*)(ws + o_logp);
  uint32_t* keys  = (uint32_t*)(ws + o_keys);
  int*      aidx  = (int*)(ws + o_aidx);
  int*      nidx  = (int*)(ws + o_nidx);
  float*    ghat  = (float*)(ws + o_ghat);

  hipMemsetAsync(ws + o_norm2, 0, (size_t)P_ * 4, stream);
  hipMemsetAsync(d_out, 0, (size_t)out_size * 4, stream);

  k_keys<<<1, 64, 0, stream>>>(keys);
  k_classify<<<256, 256, 0, stream>>>(label, mask, prob, cls, hrd);
  k_pack<<<dim3(P_ / 64, C_ / 64), 256, 0, stream>>>(mu, sg, pair8, norm2);
  k_count<<<256, 256, 0, stream>>>(cls, hrd, bcv, bch);
  k_scan<<<1, 320, 0, stream>>>(bcv, bch, bov, boh, cntv, cnth, basev, baseh);
  k_fill<<<256, 256, 0, stream>>>(cls, hrd, bov, boh, basev, baseh, posv, posh);
  k_sums<<<256, 256, 0, stream>>>(pair8, cls, part);
  k_proto<<<S_, 256, 0, stream>>>(part, mmu, msg, pmu, psig, phat);
  k_simlogp<<<S_, 64, 0, stream>>>(phat, psig, logp);
  k_anchors<<<S_, 256, 0, stream>>>(keys, cnth, baseh, posh, aidx);
  k_gen<<<dim3(GENV_, S_), 256, 0, stream>>>(keys, pmu, psig, ghat);
  k_sample<<<dim3(512, S_), 256, 0, stream>>>(keys, logp, cntv, basev, posv, nidx);
  k_main<<<S_ * Q_, 256, 0, stream>>>(pair8, norm2, phat, psig, ghat, aidx, nidx, (float*)d_out);
}

// Round 5
// 668.118 us; speedup vs baseline: 2.0998x; 1.1918x over previous
//
#include <hip/hip_runtime.h>
#include <hip/hip_fp16.h>
#include <hip/hip_fp8.h>
#include <cstdint>

#define B_   4
#define S_   19
#define HW_  16384
#define P_   65536
#define C_   256
#define Q_   256
#define NEG_ 512
#define NS_  131072
#define GENV_ 144
#define NANCH (S_ * Q_)      // 4864
#define NPAIR (NANCH / 2)    // 2432
#define NBUCK 8

typedef float v2f __attribute__((ext_vector_type(2)));

#if __has_builtin(__builtin_amdgcn_cvt_pk_f32_fp8) && __has_builtin(__builtin_amdgcn_cvt_pk_fp8_f32)
#define HAVE_HW_FP8 1
#endif

template<int W> __device__ __forceinline__ v2f cvt8(uint32_t d) {
#ifdef HAVE_HW_FP8
  v2f r = __builtin_amdgcn_cvt_pk_f32_fp8((int)d, W);
  return r;
#else
  __hip_fp8_e4m3 h0, h1;
  h0.__x = (uint8_t)(d >> (W * 16));
  h1.__x = (uint8_t)(d >> (W * 16 + 8));
  v2f r; r.x = (float)h0; r.y = (float)h1; return r;
#endif
}
template<int W> __device__ __forceinline__ uint32_t pk8(float a, float b, uint32_t old) {
#ifdef HAVE_HW_FP8
  return (uint32_t)__builtin_amdgcn_cvt_pk_fp8_f32(a, b, (int)old, W);
#else
  __hip_fp8_e4m3 ha(a), hb(b);
  uint32_t v = (uint32_t)ha.__x | ((uint32_t)hb.__x << 8);
  return (old & (W ? 0x0000FFFFu : 0xFFFF0000u)) | (v << (W * 16));
#endif
}

// ---------------- threefry2x32 (JAX-exact) ----------------
__device__ __forceinline__ void tf2x32(uint32_t k0, uint32_t k1, uint32_t x0, uint32_t x1,
                                       uint32_t& o0, uint32_t& o1) {
  uint32_t k2 = k0 ^ k1 ^ 0x1BD11BDAu;
#define TFR(r) { x0 += x1; x1 = (x1 << r) | (x1 >> (32 - r)); x1 ^= x0; }
  x0 += k0; x1 += k1;
  TFR(13) TFR(15) TFR(26) TFR(6)  x0 += k1; x1 += k2 + 1u;
  TFR(17) TFR(29) TFR(16) TFR(24) x0 += k2; x1 += k0 + 2u;
  TFR(13) TFR(15) TFR(26) TFR(6)  x0 += k0; x1 += k1 + 3u;
  TFR(17) TFR(29) TFR(16) TFR(24) x0 += k1; x1 += k2 + 4u;
  TFR(13) TFR(15) TFR(26) TFR(6)  x0 += k2; x1 += k0 + 5u;
#undef TFR
  o0 = x0; o1 = x1;
}

__device__ __forceinline__ uint32_t rbits(uint32_t k0, uint32_t k1, uint32_t n) {
  uint32_t a, b; tf2x32(k0, k1, 0u, n, a, b); return a ^ b;
}

__device__ __forceinline__ float bits2f01(uint32_t b) {
  return __uint_as_float((b >> 9) | 0x3f800000u) - 1.0f;
}

__device__ __forceinline__ float fastrcp(float x) {
  float r; asm("v_rcp_f32 %0, %1" : "=v"(r) : "v"(x)); return r;
}

__device__ __forceinline__ float wred(float v) {
#pragma unroll
  for (int off = 32; off > 0; off >>= 1) v += __shfl_xor(v, off, 64);
  return v;
}
__device__ __forceinline__ void wred3(float& a, float& b, float& c) {
#pragma unroll
  for (int off = 32; off > 0; off >>= 1) {
    a += __shfl_xor(a, off, 64);
    b += __shfl_xor(b, off, 64);
    c += __shfl_xor(c, off, 64);
  }
}

__device__ __forceinline__ void lse_up(float lg, float& m, float& l) {
  if (lg > m) { l = l * __expf(m - lg) + 1.0f; m = lg; }
  else l += __expf(lg - m);
}
__device__ __forceinline__ void lse_merge(float& m, float& l, float mo, float lo) {
  float mn = fmaxf(m, mo);
  l = l * __expf(m - mn) + lo * __expf(mo - mn);
  m = mn;
}

// XLA ErfInv32 (Giles)
__device__ __forceinline__ float erfinv_f(float x) {
  float w = -__logf(fmaxf(fmaf(-x, x, 1.0f), 1e-37f));
  float p;
  if (w < 5.0f) {
    w -= 2.5f;
    p = 2.81022636e-08f;
    p = fmaf(p, w, 3.43273939e-07f);
    p = fmaf(p, w, -3.5233877e-06f);
    p = fmaf(p, w, -4.39150654e-06f);
    p = fmaf(p, w, 0.00021858087f);
    p = fmaf(p, w, -0.00125372503f);
    p = fmaf(p, w, -0.00417768164f);
    p = fmaf(p, w, 0.246640727f);
    p = fmaf(p, w, 1.50140941f);
  } else {
    w = sqrtf(w) - 3.0f;
    p = -0.000200214257f;
    p = fmaf(p, w, 0.000100950558f);
    p = fmaf(p, w, 0.00134934322f);
    p = fmaf(p, w, -0.00367342844f);
    p = fmaf(p, w, 0.00573950773f);
    p = fmaf(p, w, -0.0076224613f);
    p = fmaf(p, w, 0.00943887047f);
    p = fmaf(p, w, 1.00167406f);
    p = fmaf(p, w, 2.83297682f);
  }
  return p * x;
}

// ---------------- K0: per-class keys ----------------
__global__ void k_keys(uint32_t* __restrict__ keys) {
  int i = threadIdx.x;
  if (i >= S_) return;
  uint32_t f0, f1;
  tf2x32(0u, 1234u, 0u, (uint32_t)i, f0, f1);
#pragma unroll
  for (int t = 0; t < 4; ++t) {
    uint32_t a, b;
    tf2x32(f0, f1, 0u, (uint32_t)t, a, b);
    keys[i * 8 + t * 2] = a; keys[i * 8 + t * 2 + 1] = b;
  }
}

// ---------------- K1: class id + hard flag ----------------
__global__ __launch_bounds__(256) void k_classify(const float* __restrict__ label,
    const float* __restrict__ mask, const float* __restrict__ prob,
    int* __restrict__ cls, int* __restrict__ hrd) {
  int p = blockIdx.x * 256 + threadIdx.x;
  int b = p >> 14, rem = p & (HW_ - 1);
  int sp = -1;
#pragma unroll
  for (int s = 0; s < S_; ++s) {
    float l = label[((b * S_ + s) << 14) + rem];
    if (l > 0.5f) sp = s;
  }
  if (mask[(b << 14) + rem] <= 0.5f) sp = -1;
  int h = 0;
  if (sp >= 0) h = (prob[((b * S_ + sp) << 14) + rem] < 0.97f) ? 1 : 0;
  cls[p] = sp; hrd[p] = h;
}

// ---------------- K1b: pack (B,C,H,W) f32 -> (P,C) fp8 pair + norm2 ----------------
__global__ __launch_bounds__(256) void k_pack(const float* __restrict__ mu,
    const float* __restrict__ sg, uint32_t* __restrict__ pair8, float* __restrict__ norm2) {
  __shared__ float smu[64][65];
  __shared__ float ssg[64][65];
  int p0 = blockIdx.x * 64, c0 = blockIdx.y * 64;
  int b = p0 >> 14, rem0 = p0 & (HW_ - 1);
  int px = threadIdx.x & 63, cy = threadIdx.x >> 6;
#pragma unroll
  for (int itr = 0; itr < 16; ++itr) {
    int cl = cy + itr * 4;
    int addr = ((b * C_ + c0 + cl) << 14) + rem0 + px;
    smu[cl][px] = mu[addr];
    ssg[cl][px] = sg[addr];
  }
  __syncthreads();
#pragma unroll
  for (int itr = 0; itr < 8; ++itr) {
    int e = itr * 256 + threadIdx.x;
    int pxl = e >> 5, dw = e & 31, cl = dw * 2;
    uint32_t wd = pk8<0>(smu[cl][pxl], ssg[cl][pxl], 0u);
    wd = pk8<1>(smu[cl + 1][pxl], ssg[cl + 1][pxl], wd);
    pair8[(size_t)(p0 + pxl) * 128 + (c0 >> 1) + dw] = wd;
  }
  int pxn = threadIdx.x >> 2, qn = threadIdx.x & 3;
  float s2 = 0.f;
#pragma unroll
  for (int k = 0; k < 16; ++k) { float v = smu[qn * 16 + k][pxn]; s2 = fmaf(v, v, s2); }
  s2 += __shfl_xor(s2, 1, 64);
  s2 += __shfl_xor(s2, 2, 64);
  if (qn == 0) atomicAdd(&norm2[p0 + pxn], s2);
}

// ---------------- K2: ordered per-class pixel lists ----------------
__global__ __launch_bounds__(256) void k_count(const int* __restrict__ cls, const int* __restrict__ hrd,
    int* __restrict__ bcv, int* __restrict__ bch) {
  __shared__ int hv[S_], hh[S_];
  int t = threadIdx.x;
  if (t < S_) { hv[t] = 0; hh[t] = 0; }
  __syncthreads();
  int p = blockIdx.x * 256 + t;
  int s = cls[p];
  if (s >= 0) { atomicAdd(&hv[s], 1); if (hrd[p]) atomicAdd(&hh[s], 1); }
  __syncthreads();
  if (t < S_) { bcv[t * 256 + blockIdx.x] = hv[t]; bch[t * 256 + blockIdx.x] = hh[t]; }
}

// parallel two-level scan: 304 workers of 16-entry chunks
__global__ __launch_bounds__(320) void k_scan(const int* __restrict__ bcv, const int* __restrict__ bch,
    int* __restrict__ bov, int* __restrict__ boh,
    int* __restrict__ cntv, int* __restrict__ cnth,
    int* __restrict__ basev, int* __restrict__ baseh) {
  __shared__ int psv[S_][16], psh[S_][16], scv[S_], sch[S_];
  int t = threadIdx.x;
  int s = t >> 4, c = t & 15;
  if (t < 304) {
    int sv = 0, sh = 0;
#pragma unroll 4
    for (int b = 0; b < 16; ++b) {
      sv += bcv[s * 256 + c * 16 + b];
      sh += bch[s * 256 + c * 16 + b];
    }
    psv[s][c] = sv; psh[s][c] = sh;
  }
  __syncthreads();
  if (t < S_) {
    int rv = 0, rh = 0;
#pragma unroll
    for (int cc = 0; cc < 16; ++cc) {
      int tv = psv[t][cc]; psv[t][cc] = rv; rv += tv;
      int th = psh[t][cc]; psh[t][cc] = rh; rh += th;
    }
    cntv[t] = rv; cnth[t] = rh; scv[t] = rv; sch[t] = rh;
  }
  __syncthreads();
  if (t == 0) {
    int bv = 0, bh = 0;
    for (int k = 0; k < S_; ++k) { basev[k] = bv; bv += scv[k]; baseh[k] = bh; bh += sch[k]; }
  }
  if (t < 304) {
    int rv = psv[s][c], rh = psh[s][c];
#pragma unroll 4
    for (int b = 0; b < 16; ++b) {
      int i0 = s * 256 + c * 16 + b;
      int tv = bcv[i0]; bov[i0] = rv; rv += tv;
      int th = bch[i0]; boh[i0] = rh; rh += th;
    }
  }
}

__global__ __launch_bounds__(256) void k_fill(const int* __restrict__ cls, const int* __restrict__ hrd,
    const int* __restrict__ bov, const int* __restrict__ boh,
    const int* __restrict__ basev, const int* __restrict__ baseh,
    int* __restrict__ posv, int* __restrict__ posh) {
  __shared__ int lc[256], lh[256];
  int t = threadIdx.x;
  int p = blockIdx.x * 256 + t;
  int s = cls[p]; int h = hrd[p];
  lc[t] = s; lh[t] = h;
  __syncthreads();
  if (s >= 0) {
    int rv = 0, rh = 0;
    for (int k = 0; k < t; ++k) { if (lc[k] == s) { rv++; rh += lh[k]; } }
    posv[basev[s] + bov[s * 256 + blockIdx.x] + rv] = p;
    if (h) posh[baseh[s] + boh[s * 256 + blockIdx.x] + rh] = p;
  }
}

// ---------------- K3: per-class partial sums (no global atomics) ----------------
__global__ __launch_bounds__(256) void k_sums(const uint32_t* __restrict__ pair8,
    const int* __restrict__ cls, float* __restrict__ part) {
  __shared__ float lacc[S_][2][C_];
  __shared__ int scls[256];
  int t = threadIdx.x;
  for (int e = t; e < S_ * 2 * C_; e += 256) (&lacc[0][0][0])[e] = 0.f;
  int p0 = blockIdx.x * 256;
  scls[t] = cls[p0 + t];
  __syncthreads();
  int half = t & 1, dwi = t >> 1;
  uint32_t d = pair8[(size_t)p0 * 128 + dwi];
  for (int pp = 0; pp < 256; ++pp) {
    uint32_t dnx = (pp + 1 < 256) ? pair8[(size_t)(p0 + pp + 1) * 128 + dwi] : 0u;
    int s = scls[pp];
    if (s >= 0) {
      v2f e = half ? cvt8<1>(d) : cvt8<0>(d);
      float ia = fastrcp(e.y);
      lacc[s][0][t] += ia;
      lacc[s][1][t] += ia * e.x;
    }
    d = dnx;
  }
  __syncthreads();
  float* dst = part + (size_t)blockIdx.x * (2 * S_ * C_);
  for (int e = t; e < S_ * 2 * C_; e += 256) dst[e] = (&lacc[0][0][0])[e];
}

// ---------------- K4: prototypes (reduce partials here) ----------------
__global__ __launch_bounds__(256) void k_proto(const float* __restrict__ part,
    const float* __restrict__ mmu, const float* __restrict__ msg,
    float* __restrict__ pmu, float* __restrict__ psig, float* __restrict__ phat) {
  int s = blockIdx.x, c = threadIdx.x;
  float A = 0.f, Bv = 0.f;
  for (int b = 0; b < 256; ++b) {
    const float* pb = part + (size_t)b * (2 * S_ * C_) + (s * 2) * C_;
    A += pb[c];
    Bv += pb[C_ + c];
  }
  int e = s * C_ + c;
  float psb = 1.0f / A;
  float pmb = psb * Bv;
  float ms = msg[e], mm = mmu[e];
  float ps = 1.0f / (1.0f / psb + 1.0f / ms);
  float pm = ps * (mm / ms + pmb / psb);
  pmu[e] = pm; psig[e] = ps;
  __shared__ float red[4];
  float w = wred(pm * pm);
  int lane = c & 63, wv = c >> 6;
  if (lane == 0) red[wv] = w;
  __syncthreads();
  float tot = red[0] + red[1] + red[2] + red[3];
  float nrm = fmaxf(sqrtf(tot), 1e-12f);
  phat[e] = pm / nrm;
}

// ---------------- K5a: sim -> log_softmax ----------------
__global__ __launch_bounds__(64) void k_simlogp(const float* __restrict__ phat,
    const float* __restrict__ psig, float* __restrict__ logp) {
  int i = blockIdx.x, lane = threadIdx.x;
  int c0 = lane * 4;
  float phi[4], psi[4];
#pragma unroll
  for (int k = 0; k < 4; ++k) { phi[k] = phat[i * C_ + c0 + k]; psi[k] = psig[i * C_ + c0 + k]; }
  float xs[18];
#pragma unroll
  for (int j = 0; j < 18; ++j) {
    int o = i + 1 + j; if (o >= S_) o -= S_;
    float t = 0.f;
#pragma unroll
    for (int k = 0; k < 4; ++k) {
      float d = phi[k] - phat[o * C_ + c0 + k];
      float dn = psi[k] + psig[o * C_ + c0 + k];
      t += d * d / dn + logf(dn);
    }
    t = wred(t);
    xs[j] = (-0.5f * t * (1.0f / 256.0f)) * 2.0f;
  }
  float m = xs[0];
#pragma unroll
  for (int j = 1; j < 18; ++j) m = fmaxf(m, xs[j]);
  float se = 0.f;
#pragma unroll
  for (int j = 0; j < 18; ++j) se += expf(xs[j] - m);
  float lg = logf(se);
  if (lane == 0) {
#pragma unroll
    for (int j = 0; j < 18; ++j) logp[i * 18 + j] = xs[j] - m - lg;
  }
}

// ---------------- K5d: anchors ----------------
__global__ __launch_bounds__(256) void k_anchors(const uint32_t* __restrict__ keys,
    const int* __restrict__ cnth, const int* __restrict__ baseh,
    const int* __restrict__ posh, int* __restrict__ aidx) {
  int i = blockIdx.x, q = threadIdx.x;
  uint32_t k0 = keys[i * 8 + 0], k1 = keys[i * 8 + 1];
  float u = bits2f01(rbits(k0, k1, (uint32_t)q));
  int cnt = cnth[i];
  int idx = P_ - 1;
  if (cnt > 0) {
    int kk = (int)(u * (float)cnt);
    if (kk >= cnt) kk = cnt - 1;
    idx = posh[baseh[i] + kk];
  }
  aidx[i * Q_ + q] = idx;
}

// ---------------- K5c: generalized prototypes ----------------
__global__ __launch_bounds__(256) void k_gen(const uint32_t* __restrict__ keys,
    const float* __restrict__ pmu, const float* __restrict__ psig, float* __restrict__ ghat) {
  int v = blockIdx.x, i = blockIdx.y, c = threadIdx.x;
  int o = i + 1 + (v >> 3); if (o >= S_) o -= S_;
  uint32_t k0 = keys[i * 8 + 6], k1 = keys[i * 8 + 7];
  uint32_t bits = rbits(k0, k1, (uint32_t)(v * C_ + c));
  float f01 = bits2f01(bits);
  const float lo = -0.99999994f;
  float u = fmaxf(f01 * 2.0f + lo, lo);
  float eps = 1.41421356237f * erfinv_f(u);
  float g = pmu[o * C_ + c] + sqrtf(psig[o * C_ + c]) * eps;
  __shared__ float red[4];
  float w = wred(g * g);
  int lane = c & 63, wv = c >> 6;
  if (lane == 0) red[wv] = w;
  __syncthreads();
  float tot = red[0] + red[1] + red[2] + red[3];
  float nrm = fmaxf(sqrtf(tot), 1e-12f);
  ghat[((size_t)(i * GENV_ + v)) * C_ + c] = g / nrm;
}

// ---------------- K5b: class + negative sampling ----------------
__global__ __launch_bounds__(256) void k_sample(const uint32_t* __restrict__ keys,
    const float* __restrict__ logp, const int* __restrict__ cntv, const int* __restrict__ basev,
    const int* __restrict__ posv, int* __restrict__ nidx) {
  int i = blockIdx.y;
  int m = blockIdx.x * 256 + threadIdx.x;
  __shared__ float lp[18];
  __shared__ int lcnt[S_], lbase[S_];
  int t = threadIdx.x;
  if (t < 18) lp[t] = logp[i * 18 + t];
  if (t < S_) { lcnt[t] = cntv[t]; lbase[t] = basev[t]; }
  __syncthreads();
  uint32_t kc0 = keys[i * 8 + 2], kc1 = keys[i * 8 + 3];
  uint32_t kn0 = keys[i * 8 + 4], kn1 = keys[i * 8 + 5];
  float bv = -1e30f; int best = 0;
  for (int s = 0; s < 18; ++s) {
    uint32_t b = rbits(kc0, kc1, (uint32_t)m * 18u + (uint32_t)s);
    float u = fmaxf(bits2f01(b), 1.17549435e-38f);
    float g = -__logf(-__logf(u)) + lp[s];
    if (g > bv) { bv = g; best = s; }
  }
  float un = bits2f01(rbits(kn0, kn1, (uint32_t)m));
  int cc = i + 1 + best; if (cc >= S_) cc -= S_;
  int cnt = lcnt[cc];
  int idx = P_ - 1;
  if (cnt > 0) {
    int kk = (int)(un * (float)cnt);
    if (kk >= cnt) kk = cnt - 1;
    idx = posv[lbase[cc] + kk];
  }
  nidx[(size_t)i * NS_ + m] = idx;
}

// ---------------- K5e: per-anchor bucket sort of negatives (deterministic) ----------------
__global__ __launch_bounds__(64) void k_bucket(const int* __restrict__ nidx,
    int* __restrict__ snidx, int* __restrict__ boff) {
  int a = blockIdx.x;
  int lane = threadIdx.x;
  const int* src = nidx + (size_t)a * NEG_;
  int e[8], bk[8];
#pragma unroll
  for (int c = 0; c < 8; ++c) { e[c] = src[c * 64 + lane]; bk[c] = (e[c] >> 13) & 7; }
  uint32_t cnt[NBUCK];
#pragma unroll
  for (int b = 0; b < NBUCK; ++b) cnt[b] = 0;
#pragma unroll
  for (int c = 0; c < 8; ++c)
#pragma unroll
    for (int b = 0; b < NBUCK; ++b) {
      unsigned long long mb = __ballot(bk[c] == b);
      cnt[b] += (uint32_t)__popcll(mb);
    }
  uint32_t base[NBUCK]; uint32_t run = 0;
#pragma unroll
  for (int b = 0; b < NBUCK; ++b) { base[b] = run; run += cnt[b]; }
  if (lane < NBUCK) boff[a * 9 + lane] = (int)base[lane];
  if (lane == 0) boff[a * 9 + 8] = NEG_;
  uint32_t off[NBUCK];
#pragma unroll
  for (int b = 0; b < NBUCK; ++b) off[b] = 0;
  unsigned long long ltm = (1ull << lane) - 1ull;
#pragma unroll
  for (int c = 0; c < 8; ++c) {
    int pos = 0;
#pragma unroll
    for (int b = 0; b < NBUCK; ++b) {
      unsigned long long mb = __ballot(bk[c] == b);
      if (bk[c] == b) pos = (int)(base[b] + off[b] + (uint32_t)__popcll(mb & ltm));
      off[b] += (uint32_t)__popcll(mb);
    }
    snidx[(size_t)a * NEG_ + pos] = e[c];
  }
}

// ---------------- K6a: negatives, bucket-major for L2 residency ----------------
__global__ __launch_bounds__(64) void k_neg(const uint32_t* __restrict__ pair8,
    const float* __restrict__ norm2, const int* __restrict__ snidx,
    const int* __restrict__ boff, const int* __restrict__ aidx,
    float2* __restrict__ partial) {
  __shared__ float4 anc[260];   // two regions: [0..128), [130..258) — bank-staggered
  int bid = blockIdx.x;
  int bucket = bid / NPAIR;
  int pr = bid - bucket * NPAIR;
  int a0 = pr * 2, a1 = a0 + 1;
  int lane = threadIdx.x;

  int ap0 = aidx[a0], ap1 = aidx[a1];
  float rn0 = fastrcp(fmaxf(sqrtf(norm2[ap0]), 1e-12f));
  float rn1 = fastrcp(fmaxf(sqrtf(norm2[ap1]), 1e-12f));
  uint2 d0 = ((const uint2*)(pair8 + (size_t)ap0 * 128))[lane];
  uint2 d1 = ((const uint2*)(pair8 + (size_t)ap1 * 128))[lane];
  {
    v2f ex = cvt8<0>(d0.x), ey = cvt8<1>(d0.x), ez = cvt8<0>(d0.y), ew = cvt8<1>(d0.y);
    anc[lane * 2]     = make_float4(ex.x * rn0, ex.y, ey.x * rn0, ey.y);
    anc[lane * 2 + 1] = make_float4(ez.x * rn0, ez.y, ew.x * rn0, ew.y);
    ex = cvt8<0>(d1.x); ey = cvt8<1>(d1.x); ez = cvt8<0>(d1.y); ew = cvt8<1>(d1.y);
    anc[130 + lane * 2]     = make_float4(ex.x * rn1, ex.y, ey.x * rn1, ey.y);
    anc[130 + lane * 2 + 1] = make_float4(ez.x * rn1, ez.y, ew.x * rn1, ew.y);
  }
  __syncthreads();

  int s0 = boff[a0 * 9 + bucket], e0 = boff[a0 * 9 + bucket + 1];
  int s1 = boff[a1 * 9 + bucket], e1 = boff[a1 * 9 + bucket + 1];
  int L0 = e0 - s0, L1 = e1 - s1, Lt = L0 + L1;
  const int* list0 = snidx + (size_t)a0 * NEG_ + s0;
  const int* list1 = snidx + (size_t)a1 * NEG_ + s1;

  float m0 = -1e30f, l0 = 0.f, m1 = -1e30f, l1 = 0.f;

  for (int r = 0; r * 64 < Lt; ++r) {
    int g = r * 64 + lane;
    bool act = g < Lt;
    int which = (act && g >= L0) ? 1 : 0;
    int j = which ? (g - L0) : g;
    int p = act ? (which ? list1[j] : list0[j]) : ap0;
    float rnN = fastrcp(fmaxf(sqrtf(norm2[p]), 1e-12f));
    const uint4* rp = (const uint4*)(pair8 + (size_t)p * 128);
    const float4* A = anc + which * 130;
    float sA = 0.f, sC = 0.f, sNR = 0.f, sL = 0.f;
    uint4 c0 = rp[0], c1 = rp[1];
    for (int it = 0; it < 16; ++it) {
      int nx = ((it + 1) & 15) * 2;
      uint4 n0 = rp[nx], n1 = rp[nx + 1];
      uint32_t dw[8] = {c0.x, c0.y, c0.z, c0.w, c1.x, c1.y, c1.z, c1.w};
      float prd = 1.0f;
#pragma unroll
      for (int jj = 0; jj < 8; ++jj) {
        float4 ac = A[it * 8 + jj];
        v2f ee = cvt8<0>(dw[jj]);
        float dn = ac.y + ee.y; float rr = fastrcp(dn); prd *= dn;
        sA = fmaf(ac.x * ac.x, rr, sA); float qq = ee.x * rr;
        sC = fmaf(ac.x, qq, sC); sNR = fmaf(ee.x, qq, sNR);
        ee = cvt8<1>(dw[jj]);
        dn = ac.w + ee.y; rr = fastrcp(dn); prd *= dn;
        sA = fmaf(ac.z * ac.z, rr, sA); qq = ee.x * rr;
        sC = fmaf(ac.z, qq, sC); sNR = fmaf(ee.x, qq, sNR);
      }
      sL += __logf(prd);
      c0 = n0; c1 = n1;
    }
    float tt = sA + rnN * rnN * sNR - 2.0f * rnN * sC + sL;
    float lg = -tt * (1.0f / 256.0f);
    if (act) {
      if (which) lse_up(lg, m1, l1); else lse_up(lg, m0, l0);
    }
  }
#pragma unroll
  for (int o = 32; o > 0; o >>= 1) {
    float mo = __shfl_xor(m0, o, 64), lo = __shfl_xor(l0, o, 64);
    lse_merge(m0, l0, mo, lo);
    mo = __shfl_xor(m1, o, 64); lo = __shfl_xor(l1, o, 64);
    lse_merge(m1, l1, mo, lo);
  }
  if (lane == 0) {
    partial[a0 * NBUCK + bucket] = make_float2(m0, l0);
    partial[a1 * NBUCK + bucket] = make_float2(m1, l1);
  }
}

// ---------------- K6b: pos + gens + merge partials ----------------
__global__ __launch_bounds__(256, 4) void k_fin(const uint32_t* __restrict__ pair8,
    const float* __restrict__ norm2,
    const float* __restrict__ phat, const float* __restrict__ psig,
    const float* __restrict__ ghat, const int* __restrict__ aidx,
    const float2* __restrict__ partial, float* __restrict__ out) {
  __shared__ float2 ancG[C_];   // {w, ahat*w}
  __shared__ float redm[3][4];
  __shared__ float2 mlw[4];

  int bid = blockIdx.x;
  int i = bid >> 8;
  int t = threadIdx.x, w = t >> 6, lane = t & 63;

  int ap = aidx[bid];
  uint32_t ad = pair8[(size_t)ap * 128 + (t >> 1)];
  v2f ae0 = cvt8<0>(ad), ae1 = cvt8<1>(ad);
  float amu = (t & 1) ? ae1.x : ae0.x;
  float asg = (t & 1) ? ae1.y : ae0.y;
  float rn = fastrcp(fmaxf(sqrtf(norm2[ap]), 1e-12f));
  float ahat = amu * rn;
  float wv = fastrcp(asg);
  ancG[t] = make_float2(wv, ahat * wv);

  float pm = phat[i * C_ + t];
  float ps = psig[i * C_ + t];
  float dnp = asg + ps;
  float dd = ahat - pm;
  float post = fmaf(dd * dd, fastrcp(dnp), __logf(dnp));
  float a1t = ahat * ahat * wv;
  float lat = __logf(asg);
  wred3(post, a1t, lat);
  if (lane == 0) { redm[0][w] = post; redm[1][w] = a1t; redm[2][w] = lat; }
  __syncthreads();
  float postS = redm[0][0] + redm[0][1] + redm[0][2] + redm[0][3];
  float Kc = (redm[1][0] + redm[1][1] + redm[1][2] + redm[1][3])
           + (redm[2][0] + redm[2][1] + redm[2][2] + redm[2][3]);
  float logit0 = -postS * (1.0f / 256.0f);

  float m = -1e30f, l = 0.0f;
  const float4* ancGf = (const float4*)ancG;
  if (lane < 36) {
    int g = lane * 4 + w;
    const float4* gp = (const float4*)(ghat + ((size_t)(i * GENV_ + g)) * C_);
    float a1 = 0.f, a2 = 0.f;
    for (int itr = 0; itr < 64; ++itr) {
      float4 gv = gp[itr];
      float4 g01 = ancGf[itr * 2];
      float4 g23 = ancGf[itr * 2 + 1];
      a1 = fmaf(gv.x * gv.x, g01.x, a1); a2 = fmaf(gv.x, g01.y, a2);
      a1 = fmaf(gv.y * gv.y, g01.z, a1); a2 = fmaf(gv.y, g01.w, a2);
      a1 = fmaf(gv.z * gv.z, g23.x, a1); a2 = fmaf(gv.z, g23.y, a2);
      a1 = fmaf(gv.w * gv.w, g23.z, a1); a2 = fmaf(gv.w, g23.w, a2);
    }
    float lg = -(Kc + a1 - 2.0f * a2) * (1.0f / 256.0f);
    lse_up(lg, m, l);
  }
#pragma unroll
  for (int o = 32; o > 0; o >>= 1) {
    float mo = __shfl_xor(m, o, 64);
    float lo = __shfl_xor(l, o, 64);
    lse_merge(m, l, mo, lo);
  }
  if (lane == 0) mlw[w] = make_float2(m, l);
  __syncthreads();
  if (t == 0) {
    float mm = mlw[0].x, ll = mlw[0].y;
    lse_merge(mm, ll, mlw[1].x, mlw[1].y);
    lse_merge(mm, ll, mlw[2].x, mlw[2].y);
    lse_merge(mm, ll, mlw[3].x, mlw[3].y);
    const float2* pp = partial + (size_t)bid * NBUCK;
#pragma unroll
    for (int b = 0; b < NBUCK; ++b) lse_merge(mm, ll, pp[b].x, pp[b].y);
    lse_merge(mm, ll, logit0, 1.0f);
    float lse = mm + __logf(ll);
    float contrib = logit0 - lse;
    atomicAdd(out, -contrib * (1.0f / (19.0f * 256.0f)));
  }
}

// ---------------- host ----------------
extern "C" void kernel_launch(void* const* d_in, const int* in_sizes, int n_in,
                              void* d_out, int out_size, void* d_ws, size_t ws_size,
                              hipStream_t stream) {
  const float* mu    = (const float*)d_in[0];
  const float* sg    = (const float*)d_in[1];
  const float* label = (const float*)d_in[2];
  const float* mask  = (const float*)d_in[3];
  const float* prob  = (const float*)d_in[4];
  const float* mmu   = (const float*)d_in[5];
  const float* msg   = (const float*)d_in[6];

  char* ws = (char*)d_ws;
  size_t off = 0;
  auto take = [&](size_t bytes) { size_t r = off; off = (off + bytes + 255) & ~(size_t)255; return r; };
  size_t o_pair8 = take((size_t)P_ * 128 * 4);   // 32 MB
  size_t o_norm2 = take((size_t)P_ * 4);
  size_t o_cls   = take((size_t)P_ * 4);
  size_t o_hrd   = take((size_t)P_ * 4);
  size_t o_bcv   = take(S_ * 256 * 4);
  size_t o_bch   = take(S_ * 256 * 4);
  size_t o_bov   = take(S_ * 256 * 4);
  size_t o_boh   = take(S_ * 256 * 4);
  size_t o_cntv  = take(S_ * 4);
  size_t o_cnth  = take(S_ * 4);
  size_t o_basev = take(S_ * 4);
  size_t o_baseh = take(S_ * 4);
  size_t o_posv  = take((size_t)P_ * 4);
  size_t o_posh  = take((size_t)P_ * 4);
  size_t o_part  = take((size_t)256 * 2 * S_ * C_ * 4);
  size_t o_pmu   = take(S_ * C_ * 4);
  size_t o_psig  = take(S_ * C_ * 4);
  size_t o_phat  = take(S_ * C_ * 4);
  size_t o_logp  = take(S_ * 18 * 4);
  size_t o_keys  = take(S_ * 8 * 4);
  size_t o_aidx  = take(S_ * Q_ * 4);
  size_t o_nidx  = take((size_t)S_ * NS_ * 4);
  size_t o_snidx = take((size_t)S_ * NS_ * 4);
  size_t o_boff  = take((size_t)NANCH * 9 * 4);
  size_t o_lpar  = take((size_t)NANCH * NBUCK * 8);
  size_t o_ghat  = take((size_t)S_ * GENV_ * C_ * 4);
  if (ws_size < off) return;

  uint32_t* pair8 = (uint32_t*)(ws + o_pair8);
  float*    norm2 = (float*)(ws + o_norm2);
  int*      cls   = (int*)(ws + o_cls);
  int*      hrd   = (int*)(ws + o_hrd);
  int*      bcv   = (int*)(ws + o_bcv);
  int*      bch   = (int*)(ws + o_bch);
  int*      bov   = (int*)(ws + o_bov);
  int*      boh   = (int*)(ws + o_boh);
  int*      cntv  = (int*)(ws + o_cntv);
  int*      cnth  = (int*)(ws + o_cnth);
  int*      basev = (int*)(ws + o_basev);
  int*      baseh = (int*)(ws + o_baseh);
  int*      posv  = (int*)(ws + o_posv);
  int*      posh  = (int*)(ws + o_posh);
  float*    part  = (float*)(ws + o_part);
  float*    pmu   = (float*)(ws + o_pmu);
  float*    psig  = (float*)(ws + o_psig);
  float*    phat  = (float*)(ws + o_phat);
  float*    logp  = (float*)(ws + o_logp);
  uint32_t* keys  = (uint32_t*)(ws + o_keys);
  int*      aidx  = (int*)(ws + o_aidx);
  int*      nidx  = (int*)(ws + o_nidx);
  int*      snidx = (int*)(ws + o_snidx);
  int*      boff  = (int*)(ws + o_boff);
  float2*   lpar  = (float2*)(ws + o_lpar);
  float*    ghat  = (float*)(ws + o_ghat);

  hipMemsetAsync(ws + o_norm2, 0, (size_t)P_ * 4, stream);
  hipMemsetAsync(d_out, 0, (size_t)out_size * 4, stream);

  k_keys<<<1, 64, 0, stream>>>(keys);
  k_classify<<<256, 256, 0, stream>>>(label, mask, prob, cls, hrd);
  k_pack<<<dim3(P_ / 64, C_ / 64), 256, 0, stream>>>(mu, sg, pair8, norm2);
  k_count<<<256, 256, 0, stream>>>(cls, hrd, bcv, bch);
  k_scan<<<1, 320, 0, stream>>>(bcv, bch, bov, boh, cntv, cnth, basev, baseh);
  k_fill<<<256, 256, 0, stream>>>(cls, hrd, bov, boh, basev, baseh, posv, posh);
  k_sums<<<256, 256, 0, stream>>>(pair8, cls, part);
  k_proto<<<S_, 256, 0, stream>>>(part, mmu, msg, pmu, psig, phat);
  k_simlogp<<<S_, 64, 0, stream>>>(phat, psig, logp);
  k_anchors<<<S_, 256, 0, stream>>>(keys, cnth, baseh, posh, aidx);
  k_gen<<<dim3(GENV_, S_), 256, 0, stream>>>(keys, pmu, psig, ghat);
  k_sample<<<dim3(512, S_), 256, 0, stream>>>(keys, logp, cntv, basev, posv, nidx);
  k_bucket<<<NANCH, 64, 0, stream>>>(nidx, snidx, boff);
  k_neg<<<NBUCK * NPAIR, 64, 0, stream>>>(pair8, norm2, snidx, boff, aidx, lpar);
  k_fin<<<NANCH, 256, 0, stream>>>(pair8, norm2, phat, psig, ghat, aidx, lpar, (float*)d_out);
}